// Round 13
// baseline (155.390 us; speedup 1.0000x reference)
//
#include <hip/hip_runtime.h>
#include <hip/hip_bf16.h>
#include <stdint.h>

typedef __bf16 bf16;
typedef __bf16 bf16x8 __attribute__((ext_vector_type(8)));
typedef __bf16 bf16x4 __attribute__((ext_vector_type(4)));
typedef float  f32x4  __attribute__((ext_vector_type(4)));
typedef float  f32x16 __attribute__((ext_vector_type(16)));
typedef uint32_t u32;

#define MFMA16(a,b,c) __builtin_amdgcn_mfma_f32_16x16x32_bf16((a),(b),(c),0,0,0)
#define MFMA32(a,b,c) __builtin_amdgcn_mfma_f32_32x32x16_bf16((a),(b),(c),0,0,0)

// 0.125 (1/sqrt(64)) * log2(e): folded into Wq/bq so softmax runs in exp2 domain.
#define QSCL 0.1803368801111204f

// ---------- helpers ----------
__device__ __forceinline__ u32 sx32(u32 x) {  // value from lane^32 (HW-verified r3)
    return (u32)__shfl_xor((int)x, 32, 64);
}
__device__ __forceinline__ float swapred_max(float v) {
    return fmaxf(v, __builtin_bit_cast(float, sx32(__builtin_bit_cast(u32, v))));
}
__device__ __forceinline__ float swapred_sum(float v) {
    return v + __builtin_bit_cast(float, sx32(__builtin_bit_cast(u32, v)));
}
__device__ __forceinline__ u32 pkbf(float lo, float hi) {
    union { bf16 h[2]; u32 u; } un;
    un.h[0] = (bf16)lo; un.h[1] = (bf16)hi;
    return un.u;
}
__device__ __forceinline__ void glds16(const bf16* src, bf16* ldsDst) {
    __builtin_amdgcn_global_load_lds(
        (const __attribute__((address_space(1))) void*)src,
        (__attribute__((address_space(3))) void*)ldsDst, 16, 0, 0);
}
// p[16] = exp'd scores for one 32-row K-block; lane (lm,hi) holds k_local(r) =
// (r&3) + 8*(r>>2) + 4*hi for col q=lm. Produce PV B-frags f0 (k=0..15) and
// f1 (k=16..31): lane needs k = 16*ks + hi*8 + j (j=0..7) at col q=lm.
__device__ __forceinline__ void pack_frags(const float* p, int hi, bf16x8& f0, bf16x8& f1) {
    u32 k01 = pkbf(p[0],  p[1]),  k23 = pkbf(p[2],  p[3]);
    u32 k45 = pkbf(p[4],  p[5]),  k67 = pkbf(p[6],  p[7]);
    u32 k89 = pkbf(p[8],  p[9]),  kab = pkbf(p[10], p[11]);
    u32 kcd = pkbf(p[12], p[13]), kef = pkbf(p[14], p[15]);
    u32 x01 = sx32(k01), x23 = sx32(k23), x45 = sx32(k45), x67 = sx32(k67);
    u32 x89 = sx32(k89), xab = sx32(kab), xcd = sx32(kcd), xef = sx32(kef);
    union { u32 w[4]; bf16x8 v; } u0, u1;
    u0.w[0] = hi ? x45 : k01;  u0.w[1] = hi ? x67 : k23;
    u0.w[2] = hi ? k45 : x01;  u0.w[3] = hi ? k67 : x23;
    u1.w[0] = hi ? xcd : k89;  u1.w[1] = hi ? xef : kab;
    u1.w[2] = hi ? kcd : x89;  u1.w[3] = hi ? kef : xab;
    f0 = u0.v; f1 = u1.v;
}

// ---------------- fp32 -> bf16 convert (proven R10) ----------------
__global__ __launch_bounds__(256) void k_cvt3(const float* __restrict__ a, const float* __restrict__ b,
                                              const float* __restrict__ c,
                                              bf16* __restrict__ x, bf16* __restrict__ y,
                                              bf16* __restrict__ z) {
    int i = blockIdx.x * 256 + threadIdx.x;          // vec4 index, 3 * 2^20 total
    int t = i >> 20;
    int r = (i & 1048575) << 2;
    const float* s = (t == 0) ? a : ((t == 1) ? b : c);
    bf16* d = (t == 0) ? x : ((t == 1) ? y : z);
    float4 v = *(const float4*)&s[r];
    bf16x4 w = {(bf16)v.x, (bf16)v.y, (bf16)v.z, (bf16)v.w};
    *(bf16x4*)&d[r] = w;
}

// ---------------- weight transpose: W[k][n] fp32 -> Wt[n][k] bf16 (* scale) ----------------
__device__ __forceinline__ void transpose_body(const float* __restrict__ W, bf16* __restrict__ Wt,
                                               float scale, int n0, int k0) {
    __shared__ bf16 t[64][65];
    for (int i = 0; i < 16; ++i) {
        int idx = threadIdx.x + i * 256, r = idx >> 6, c = idx & 63;
        t[r][c] = (bf16)(W[(size_t)(k0 + r) * 1024 + n0 + c] * scale);
    }
    __syncthreads();
    for (int i = 0; i < 16; ++i) {
        int idx = threadIdx.x + i * 256, r = idx >> 6, c = idx & 63;
        Wt[(size_t)(n0 + r) * 1024 + k0 + c] = t[c][r];
    }
}
__global__ __launch_bounds__(256) void k_transpose_w(const float* __restrict__ W,
                                                     bf16* __restrict__ Wt, float scale) {
    transpose_body(W, Wt, scale, blockIdx.x * 64, blockIdx.y * 64);
}
__global__ __launch_bounds__(256) void k_transpose_w4(const float* __restrict__ Wq, const float* __restrict__ Wk,
                                                      const float* __restrict__ Wv, const float* __restrict__ Wo,
                                                      bf16* __restrict__ Wtq, bf16* __restrict__ Wtk,
                                                      bf16* __restrict__ Wtv, bf16* __restrict__ Wto) {
    int z = blockIdx.z;
    const float* W = (z == 0) ? Wq : (z == 1) ? Wk : (z == 2) ? Wv : Wo;
    bf16* Wt = (z == 0) ? Wtq : (z == 1) ? Wtk : (z == 2) ? Wtv : Wto;
    transpose_body(W, Wt, (z == 0) ? QSCL : 1.0f, blockIdx.x * 64, blockIdx.y * 64);
}

// ================= 256x256xK=1024 counted-vmcnt GEMM (T2+T3/T4+T5) =================
// 8 waves (512 thr), BK=64, dbuf LDS 128KB, 1 block/CU. Per K-tile two sub-phases:
//  SubA: ds_read ALL 24 frags (k0+k1) from slot s, 32 MFMA (k0), lgkmcnt(0)+s_barrier
//        -> slot s is read-free block-wide.
//  SubB: stage tile t+2 into slot s (8 glds/wave), 32 MFMA (k1, register-only),
//        s_waitcnt vmcnt(8) (NEVER 0: the 8 fresh loads stay in flight), s_barrier.
// Swizzle: LDS[row][pc]=global[row][pc^(row&7)] via pre-swizzled glds SOURCE (linear
// dest); reads XOR the chunk the same way -> 2-way bank aliasing (free).
// out_mode 0: bf16 head layout [b][h][s][d]; out_mode 2: bf16 Vt layout [bh][d][s].
__device__ __forceinline__ void gemm256(const bf16* __restrict__ Ag, const bf16* __restrict__ Bg,
                                        const float* __restrict__ bias, float bscale,
                                        bf16* __restrict__ Cp, int m0, int n0, int out_mode,
                                        bf16* As, bf16* Bs) {
    const int tid = threadIdx.x;
    const int wid = tid >> 6, lane = tid & 63;
    const int lm = lane & 15, g = lane >> 4, swz = lane & 7;
    const int wm = wid >> 2, wn = wid & 3;

    // staging geometry: wave w covers rows [w*32, w*32+32) of both operands,
    // 4 glds each (1KB = 8 rows of 128B). Source chunk pre-swizzled.
    const int rl8 = (lane >> 3) & 7;
    const int lcs = (lane & 7) ^ rl8;
    const bf16* Asrc = Ag + (size_t)(m0 + wid * 32 + rl8) * 1024 + lcs * 8;
    const bf16* Bsrc = Bg + (size_t)(n0 + wid * 32 + rl8) * 1024 + lcs * 8;

    f32x4 acc[8][4] = {};

#define STAGE256(KT, S)                                                      \
    do {                                                                     \
        _Pragma("unroll")                                                    \
        for (int j = 0; j < 4; ++j) {                                        \
            glds16(Asrc + (size_t)j * 8192 + (KT) * 64,                      \
                   As + (S) * 16384 + (wid * 4 + j) * 512);                  \
            glds16(Bsrc + (size_t)j * 8192 + (KT) * 64,                      \
                   Bs + (S) * 16384 + (wid * 4 + j) * 512);                  \
        }                                                                    \
    } while (0)

    // prologue: tiles 0,1 in flight; wait tile 0 (8 newest = tile 1 stay out)
    STAGE256(0, 0);
    STAGE256(1, 1);
    asm volatile("s_waitcnt vmcnt(8)" ::: "memory");
    __builtin_amdgcn_s_barrier();

#pragma unroll 1
    for (int t = 0; t < 16; ++t) {
        const int s = t & 1;
        const bf16* Ab = As + s * 16384;
        const bf16* Bb = Bs + s * 16384;

        // ---- SubA: read all frags of tile t, compute k0 ----
        bf16x8 af[8][2], bfr[4][2];
#pragma unroll
        for (int mf = 0; mf < 8; ++mf) {
            const bf16* rp = Ab + (wm * 128 + mf * 16 + lm) * 64;
#pragma unroll
            for (int ks = 0; ks < 2; ++ks)
                af[mf][ks] = *(const bf16x8*)(rp + ((((ks * 4 + g) ^ swz)) << 3));
        }
#pragma unroll
        for (int nf = 0; nf < 4; ++nf) {
            const bf16* rp = Bb + (wn * 64 + nf * 16 + lm) * 64;
#pragma unroll
            for (int ks = 0; ks < 2; ++ks)
                bfr[nf][ks] = *(const bf16x8*)(rp + ((((ks * 4 + g) ^ swz)) << 3));
        }
        __builtin_amdgcn_s_setprio(1);
#pragma unroll
        for (int mf = 0; mf < 8; ++mf)
#pragma unroll
            for (int nf = 0; nf < 4; ++nf)
                acc[mf][nf] = MFMA16(af[mf][0], bfr[nf][0], acc[mf][nf]);
        __builtin_amdgcn_s_setprio(0);
        __builtin_amdgcn_sched_barrier(0);
        asm volatile("s_waitcnt lgkmcnt(0)" ::: "memory");   // all reads of slot s done
        __builtin_amdgcn_sched_barrier(0);
        __builtin_amdgcn_s_barrier();                        // ... block-wide

        // ---- SubB: stage t+2 into freed slot s, compute k1 (registers only) ----
        if (t + 2 < 16) STAGE256(t + 2, s);
        __builtin_amdgcn_s_setprio(1);
#pragma unroll
        for (int mf = 0; mf < 8; ++mf)
#pragma unroll
            for (int nf = 0; nf < 4; ++nf)
                acc[mf][nf] = MFMA16(af[mf][1], bfr[nf][1], acc[mf][nf]);
        __builtin_amdgcn_s_setprio(0);
        __builtin_amdgcn_sched_barrier(0);
        if (t < 14)       asm volatile("s_waitcnt vmcnt(8)" ::: "memory"); // t+1 landed; t+2 in flight
        else if (t == 14) asm volatile("s_waitcnt vmcnt(0)" ::: "memory"); // drain t15
        __builtin_amdgcn_sched_barrier(0);
        __builtin_amdgcn_s_barrier();
    }
#undef STAGE256

    // epilogue
#pragma unroll
    for (int mf = 0; mf < 8; ++mf) {
#pragma unroll
        for (int nf = 0; nf < 4; ++nf) {
            int col = n0 + wn * 64 + nf * 16 + lm;
            for (int q = 0; q < 4; ++q) {
                int row = m0 + wm * 128 + mf * 16 + g * 4 + q;
                if (out_mode == 0) {  // bf16 head layout [b][h][s][d]
                    float val = acc[mf][nf][q] + bscale * bias[col];
                    int bb = row >> 11, sq = row & 2047, h = col >> 6, d = col & 63;
                    Cp[(((size_t)bb * 16 + h) * 2048 + sq) * 64 + d] = (bf16)val;
                } else {              // Vt layout [bh][d][s], bias per A-row
                    float val = acc[mf][nf][q] + bias[row];
                    size_t idx = (((size_t)(col >> 11) * 16 + (row >> 6)) * 64 + (row & 63)) * 2048 + (col & 2047);
                    Cp[idx] = (bf16)val;
                }
            }
        }
    }
}

// fused Q/K/V projections, 256^2 tiles: grid 192 = 3 proj x (16 m x 4 n | 4 m x 16 n)
__global__ __launch_bounds__(512, 2) void k_gemm_qkv8(const bf16* __restrict__ qc, const bf16* __restrict__ kc,
                                                      const bf16* __restrict__ vc,
                                                      const bf16* __restrict__ Wtq, const bf16* __restrict__ Wtk,
                                                      const bf16* __restrict__ Wtv,
                                                      const float* __restrict__ bq, const float* __restrict__ bk,
                                                      const float* __restrict__ bv,
                                                      bf16* __restrict__ Qb, bf16* __restrict__ Kb,
                                                      bf16* __restrict__ Vtb) {
    __shared__ bf16 As[2][16384];
    __shared__ bf16 Bs[2][16384];
    const int bid = blockIdx.x, z = bid >> 6, r = bid & 63;
    const bf16 *Ag, *Bg;
    const float* bias;
    float bscale;
    bf16* Cp;
    int m0, n0, mode;
    if (z == 2) {        // Vt = Wtv (M=1024 rows) x vc (N=4096 rows)
        Ag = Wtv; Bg = vc; bias = bv; bscale = 1.0f; Cp = Vtb;
        m0 = (r & 3) * 256; n0 = (r >> 2) * 256; mode = 2;
    } else if (z == 0) { // Q = qc (M=4096) x Wtq (N=1024)
        Ag = qc; Bg = Wtq; bias = bq; bscale = QSCL; Cp = Qb;
        m0 = (r >> 2) * 256; n0 = (r & 3) * 256; mode = 0;
    } else {             // K
        Ag = kc; Bg = Wtk; bias = bk; bscale = 1.0f; Cp = Kb;
        m0 = (r >> 2) * 256; n0 = (r & 3) * 256; mode = 0;
    }
    gemm256(Ag, Bg, bias, bscale, Cp, m0, n0, mode, &As[0][0], &Bs[0][0]);
}

// ---------------- pipelined mixed GEMM (fallback path only, proven R11/R12) ----------------
template <int F32_IS_A>
__device__ __forceinline__ void gemm_pipe(const float* __restrict__ P32, const bf16* __restrict__ P16,
                                          const float* __restrict__ bias, float bscale,
                                          void* __restrict__ Cp, int out_mode, int m0, int n0,
                                          bf16 (*S32)[64], bf16 (*L16)[64]) {
    const int tid = threadIdx.x;
    const int wid = tid >> 6, lane = tid & 63, lg = lane >> 4, lm = lane & 15;
    const int wr = wid >> 1, wc = wid & 1;
    const int grow = tid >> 3, gcol = (tid & 7) << 3;
    const int r32base = F32_IS_A ? m0 : n0;
    const int r16base = F32_IS_A ? n0 : m0;

    f32x4 acc[4][4] = {};
    float4 rA[4][2];

    auto issue32 = [&](int kt) {
#pragma unroll
        for (int p = 0; p < 4; ++p) {
            const float* src = P32 + (size_t)(r32base + p * 32 + grow) * 1024 + (kt << 6) + gcol;
            rA[p][0] = *(const float4*)src;
            rA[p][1] = *(const float4*)(src + 4);
        }
    };
    auto write32 = [&](int buf) {
#pragma unroll
        for (int p = 0; p < 4; ++p) {
            bf16x8 w = {(bf16)rA[p][0].x, (bf16)rA[p][0].y, (bf16)rA[p][0].z, (bf16)rA[p][0].w,
                        (bf16)rA[p][1].x, (bf16)rA[p][1].y, (bf16)rA[p][1].z, (bf16)rA[p][1].w};
            *(bf16x8*)&S32[buf * 128 + p * 32 + grow][gcol] = w;
        }
    };
    auto stage16 = [&](int kt, int buf) {
#pragma unroll
        for (int p = 0; p < 4; ++p)
            glds16(P16 + (size_t)(r16base + p * 32 + grow) * 1024 + (kt << 6) + gcol,
                   &L16[buf * 128 + p * 32 + wid * 8][0]);
    };

    issue32(0);
    stage16(0, 0);
    write32(0);
    __syncthreads();

    int buf = 0;
#pragma unroll 1
    for (int kt = 0; kt < 16; ++kt) {
        if (kt < 15) {
            issue32(kt + 1);
            stage16(kt + 1, buf ^ 1);
        }
#pragma unroll
        for (int kk = 0; kk < 2; ++kk) {
            bf16x8 a[4], b[4];
#pragma unroll
            for (int i = 0; i < 4; ++i) {
                if constexpr (F32_IS_A)
                    a[i] = *(const bf16x8*)&S32[buf * 128 + wr * 64 + i * 16 + lm][kk * 32 + lg * 8];
                else
                    a[i] = *(const bf16x8*)&L16[buf * 128 + wr * 64 + i * 16 + lm][kk * 32 + lg * 8];
            }
#pragma unroll
            for (int j = 0; j < 4; ++j) {
                if constexpr (F32_IS_A)
                    b[j] = *(const bf16x8*)&L16[buf * 128 + wc * 64 + j * 16 + lm][kk * 32 + lg * 8];
                else
                    b[j] = *(const bf16x8*)&S32[buf * 128 + wc * 64 + j * 16 + lm][kk * 32 + lg * 8];
            }
#pragma unroll
            for (int i = 0; i < 4; ++i)
#pragma unroll
                for (int j = 0; j < 4; ++j) acc[i][j] = MFMA16(a[i], b[j], acc[i][j]);
        }
        if (kt < 15) write32(buf ^ 1);
        __syncthreads();
        buf ^= 1;
    }

    for (int i = 0; i < 4; ++i) {
        for (int j = 0; j < 4; ++j) {
            int col = n0 + wc * 64 + j * 16 + lm;
            for (int q = 0; q < 4; ++q) {
                int row = m0 + wr * 64 + i * 16 + lg * 4 + q;
                if (out_mode == 0) {
                    float val = acc[i][j][q] + bscale * bias[col];
                    int bb = row >> 11, s = row & 2047, h = col >> 6, d = col & 63;
                    ((bf16*)Cp)[(((size_t)bb * 16 + h) * 2048 + s) * 64 + d] = (bf16)val;
                } else {
                    float val = acc[i][j][q] + bias[row];
                    size_t idx = (((size_t)(col >> 11) * 16 + (row >> 6)) * 64 + (row & 63)) * 2048 + (col & 2047);
                    ((bf16*)Cp)[idx] = (bf16)val;
                }
            }
        }
    }
}

__device__ __forceinline__ void tile_decode(int r, int& m0, int& n0) {
    int xcd = r & 7, slot = (r >> 3) & 3, n = (r >> 5) & 7;
    m0 = (xcd * 4 + slot) * 128;
    n0 = n * 128;
}
__device__ __forceinline__ void tile_decode_vt(int r, int& m0, int& n0) {
    int xcd = r & 7, loc = r >> 3;
    int nslot = loc & 3, m = loc >> 2;
    n0 = (xcd * 4 + nslot) * 128;
    m0 = m * 128;
}

__global__ __launch_bounds__(256, 2) void k_gemm_proj(const float* __restrict__ A,
                                                      const bf16* __restrict__ Bt,
                                                      const float* __restrict__ bias, float bscale,
                                                      void* __restrict__ Cp) {
    __shared__ bf16 S32[256][64];
    __shared__ bf16 L16[256][64];
    int m0, n0;
    tile_decode(blockIdx.x, m0, n0);
    gemm_pipe<1>(A, Bt, bias, bscale, Cp, 0, m0, n0, S32, L16);
}

__global__ __launch_bounds__(256, 2) void k_gemm_vt(const bf16* __restrict__ Wtv,
                                                    const float* __restrict__ v,
                                                    const float* __restrict__ bias,
                                                    bf16* __restrict__ Vtb) {
    __shared__ bf16 S32[256][64];
    __shared__ bf16 L16[256][64];
    int m0, n0;
    tile_decode_vt(blockIdx.x, m0, n0);
    gemm_pipe<0>(v, Wtv, bias, 1.0f, (void*)Vtb, 2, m0, n0, S32, L16);
}

// ---------------- output projection: 128x64 tiles, 512 blocks (2/CU) ----------------
__global__ __launch_bounds__(256, 4) void k_gemm_out(const bf16* __restrict__ A,
                                                     const bf16* __restrict__ Bt,
                                                     const float* __restrict__ bias,
                                                     float* __restrict__ C) {
    __shared__ bf16 As[128][64];
    __shared__ bf16 Bs[64][64];
    const int tid = threadIdx.x;
    const int wid = tid >> 6, lane = tid & 63, lg = lane >> 4, lm = lane & 15;
    const int grow = tid >> 3, gcol = (tid & 7) << 3;
    const int r = blockIdx.x;
    const int xcd = r & 7, loc = r >> 3;
    const int mslot = loc & 3, n = loc >> 2;
    const int m0 = (xcd * 4 + mslot) * 128, n0 = n * 64;

    f32x4 acc[2][4] = {};

    for (int kt = 0; kt < 16; ++kt) {
        const int k0 = kt << 6;
        __syncthreads();
#pragma unroll
        for (int p = 0; p < 4; ++p)
            glds16(A + (size_t)(m0 + p * 32 + grow) * 1024 + k0 + gcol, &As[p * 32 + wid * 8][0]);
#pragma unroll
        for (int p = 0; p < 2; ++p)
            glds16(Bt + (size_t)(n0 + p * 32 + grow) * 1024 + k0 + gcol, &Bs[p * 32 + wid * 8][0]);
        __syncthreads();
#pragma unroll
        for (int kk = 0; kk < 2; ++kk) {
            bf16x8 a[2], b[4];
#pragma unroll
            for (int i = 0; i < 2; ++i) a[i] = *(const bf16x8*)&As[wid * 32 + i * 16 + lm][kk * 32 + lg * 8];
#pragma unroll
            for (int j = 0; j < 4; ++j) b[j] = *(const bf16x8*)&Bs[j * 16 + lm][kk * 32 + lg * 8];
#pragma unroll
            for (int i = 0; i < 2; ++i)
#pragma unroll
                for (int j = 0; j < 4; ++j) acc[i][j] = MFMA16(a[i], b[j], acc[i][j]);
        }
    }

    for (int i = 0; i < 2; ++i) {
        for (int j = 0; j < 4; ++j) {
            int col = n0 + j * 16 + lm;
            float bv = bias[col];
            for (int q = 0; q < 4; ++q) {
                int row = m0 + wid * 32 + i * 16 + lg * 4 + q;
                C[(size_t)row * 1024 + col] = acc[i][j][q] + bv;
            }
        }
    }
}

// ---------------- flash attention: 8-wave block, LDS-staged K/V (best measured) ----------------
__global__ __launch_bounds__(512, 2) void k_attn(const bf16* __restrict__ Q,
                                                 const bf16* __restrict__ Kb,
                                                 const bf16* __restrict__ Vt,
                                                 bf16* __restrict__ Out) {
    __shared__ bf16 Ks[2][64 * 64];
    __shared__ bf16 Vs[2][64 * 64];
    const int tid = threadIdx.x;
    const int wid = tid >> 6, lane = tid & 63;
    const int lm = lane & 31, hi = lane >> 5;
    const int bid = blockIdx.x;
    const int bh = bid & 31, qt = bid >> 5;
    const int bb = bh >> 4, h = bh & 15;
    const int qrow = qt * 256 + wid * 32 + lm;
    const size_t qk_base = (size_t)bh * (2048 * 64);
    const size_t vt_base = (size_t)bh * (64 * 2048);

    const int srow = tid >> 3, sc8 = tid & 7;
    const int cse = (sc8 ^ (srow & 7)) * 8;
    const bf16* kstage = Kb + qk_base + (size_t)srow * 64 + cse;
    const bf16* vstage = Vt + vt_base + (size_t)srow * 2048 + cse;
    const int ldsoff = wid * 512;   // in bf16 units (1024 B)

    bf16x8 qf[4];
    {
        const bf16* qp = Q + qk_base + (size_t)qrow * 64 + hi * 8;
#pragma unroll
        for (int f = 0; f < 4; ++f) qf[f] = *(const bf16x8*)(qp + f * 16);
    }

    f32x16 O0 = {}, O1 = {};
    float mrow = -1e30f, lsum = 0.f;

    const int swz = (lm & 7);

    glds16(kstage, &Ks[0][0] + ldsoff);
    glds16(vstage, &Vs[0][0] + ldsoff);
    __syncthreads();

    int cur = 0;
#pragma unroll 1
    for (int kt = 0; kt < 32; ++kt) {
        if (kt + 1 < 32) {
            glds16(kstage + (size_t)(kt + 1) * 4096, &Ks[cur ^ 1][0] + ldsoff);
            glds16(vstage + (size_t)(kt + 1) * 64, &Vs[cur ^ 1][0] + ldsoff);
        }

        const char* Ksc = (const char*)&Ks[cur][0];
        const char* Vsc = (const char*)&Vs[cur][0];

        bf16x8 kf0[4], kf1[4];
#pragma unroll
        for (int f = 0; f < 4; ++f) {
            int ch = (f << 1) | hi;
            kf0[f] = *(const bf16x8*)(Ksc + lm * 128 + ((ch ^ swz) << 4));
            kf1[f] = *(const bf16x8*)(Ksc + (lm + 32) * 128 + ((ch ^ swz) << 4));
        }
        bf16x8 vf0[4], vf1[4];
#pragma unroll
        for (int ks = 0; ks < 4; ++ks) {
            int ch = (ks << 1) | hi;
            vf0[ks] = *(const bf16x8*)(Vsc + lm * 128 + ((ch ^ swz) << 4));
            vf1[ks] = *(const bf16x8*)(Vsc + (lm + 32) * 128 + ((ch ^ swz) << 4));
        }

        f32x16 s0 = {}, s1 = {};
#pragma unroll
        for (int f = 0; f < 4; ++f) {
            s0 = MFMA32(kf0[f], qf[f], s0);
            s1 = MFMA32(kf1[f], qf[f], s1);
        }

        float pe0[16], pe1[16];
#pragma unroll
        for (int r = 0; r < 16; ++r) pe0[r] = __builtin_amdgcn_exp2f(s0[r] - mrow);
#pragma unroll
        for (int r = 0; r < 16; ++r) pe1[r] = __builtin_amdgcn_exp2f(s1[r] - mrow);

        float t8[8];
#pragma unroll
        for (int r = 0; r < 8; ++r)
            t8[r] = fmaxf(fmaxf(s0[r], s0[r + 8]), fmaxf(s1[r], s1[r + 8]));
#pragma unroll
        for (int st = 4; st; st >>= 1)
#pragma unroll
            for (int r = 0; r < st; ++r) t8[r] = fmaxf(t8[r], t8[r + st]);
        float pm = swapred_max(t8[0]);

        if (!__all(pm <= mrow + 8.0f)) {
            float mnew = fmaxf(mrow, pm);
            float corr = __builtin_amdgcn_exp2f(mrow - mnew);
            lsum *= corr;
            O0 *= corr;
            O1 *= corr;
            mrow = mnew;
#pragma unroll
            for (int r = 0; r < 16; ++r) pe0[r] = __builtin_amdgcn_exp2f(s0[r] - mrow);
#pragma unroll
            for (int r = 0; r < 16; ++r) pe1[r] = __builtin_amdgcn_exp2f(s1[r] - mrow);
        }

        float u8[8];
#pragma unroll
        for (int r = 0; r < 8; ++r) u8[r] = (pe0[r] + pe0[r + 8]) + (pe1[r] + pe1[r + 8]);
#pragma unroll
        for (int st = 4; st; st >>= 1)
#pragma unroll
            for (int r = 0; r < st; ++r) u8[r] = u8[r] + u8[r + st];
        lsum += u8[0];

        bf16x8 pf[4];
        pack_frags(pe0, hi, pf[0], pf[1]);
        pack_frags(pe1, hi, pf[2], pf[3]);

#pragma unroll
        for (int ks = 0; ks < 4; ++ks) {
            O0 = MFMA32(vf0[ks], pf[ks], O0);
            O1 = MFMA32(vf1[ks], pf[ks], O1);
        }

        __syncthreads();
        cur ^= 1;
    }

    float lrow = swapred_sum(lsum);
    float inv = 1.0f / lrow;
    bf16* op = Out + ((size_t)bb * 2048 + qrow) * 1024 + h * 64 + 4 * hi;
#pragma unroll
    for (int t = 0; t < 4; ++t) {
        bf16x4 w0, w1;
#pragma unroll
        for (int e = 0; e < 4; ++e) {
            w0[e] = (bf16)(O0[4 * t + e] * inv);
            w1[e] = (bf16)(O1[4 * t + e] * inv);
        }
        *(bf16x4*)(op + 8 * t)      = w0;
        *(bf16x4*)(op + 32 + 8 * t) = w1;
    }
}

extern "C" void kernel_launch(void* const* d_in, const int* in_sizes, int n_in,
                              void* d_out, int out_size, void* d_ws, size_t ws_size,
                              hipStream_t stream) {
    const float* q  = (const float*)d_in[0];
    const float* k  = (const float*)d_in[1];
    const float* v  = (const float*)d_in[2];
    const float* Wq = (const float*)d_in[3];
    const float* bq = (const float*)d_in[4];
    const float* Wk = (const float*)d_in[5];
    const float* bk = (const float*)d_in[6];
    const float* Wv = (const float*)d_in[7];
    const float* bv = (const float*)d_in[8];
    const float* Wo = (const float*)d_in[9];
    const float* bo = (const float*)d_in[10];

    char* ws = (char*)d_ws;
    const size_t MB = 1ull << 20;
    const dim3 twg(16, 16), blk(256);

    if (ws_size >= 64 * MB) {
        // fused path (64 MB): cvt3 -> 256^2 counted-vmcnt QKV -> attn -> out
        bf16* Wtq = (bf16*)(ws + 0 * MB);
        bf16* Wtk = (bf16*)(ws + 2 * MB);
        bf16* Wtv = (bf16*)(ws + 4 * MB);
        bf16* Wto = (bf16*)(ws + 6 * MB);
        bf16* qc  = (bf16*)(ws + 8 * MB);
        bf16* kc  = (bf16*)(ws + 16 * MB);
        bf16* vc  = (bf16*)(ws + 24 * MB);
        bf16* Qb  = (bf16*)(ws + 32 * MB);
        bf16* Kb  = (bf16*)(ws + 40 * MB);
        bf16* Vtb = (bf16*)(ws + 48 * MB);
        bf16* AOb = (bf16*)(ws + 56 * MB);

        k_transpose_w4<<<dim3(16, 16, 4), blk, 0, stream>>>(Wq, Wk, Wv, Wo, Wtq, Wtk, Wtv, Wto);
        k_cvt3<<<12288, blk, 0, stream>>>(q, k, v, qc, kc, vc);
        k_gemm_qkv8<<<192, 512, 0, stream>>>(qc, kc, vc, Wtq, Wtk, Wtv, bq, bk, bv, Qb, Kb, Vtb);
        k_attn<<<256, 512, 0, stream>>>(Qb, Kb, Vtb, AOb);
        k_gemm_out<<<512, blk, 0, stream>>>(AOb, Wto, bo, (float*)d_out);
    } else {
        // sequential fallback (34 MB ws), proven R11 path
        bf16* Wt   = (bf16*)(ws + 0 * MB);
        bf16* Qb   = (bf16*)(ws + 2 * MB);
        bf16* Kb   = (bf16*)(ws + 10 * MB);
        bf16* Vtb  = (bf16*)(ws + 18 * MB);
        bf16* AOb  = (bf16*)(ws + 26 * MB);

        k_transpose_w<<<twg, blk, 0, stream>>>(Wq, Wt, QSCL);
        k_gemm_proj<<<256, blk, 0, stream>>>(q, Wt, bq, QSCL, (void*)Qb);
        k_transpose_w<<<twg, blk, 0, stream>>>(Wk, Wt, 1.0f);
        k_gemm_proj<<<256, blk, 0, stream>>>(k, Wt, bk, 1.0f, (void*)Kb);
        k_transpose_w<<<twg, blk, 0, stream>>>(Wv, Wt, 1.0f);
        k_gemm_vt<<<256, blk, 0, stream>>>(Wt, v, bv, Vtb);
        k_transpose_w<<<twg, blk, 0, stream>>>(Wo, Wt, 1.0f);
        k_attn<<<256, 512, 0, stream>>>(Qb, Kb, Vtb, AOb);
        k_gemm_out<<<512, blk, 0, stream>>>(AOb, Wt, bo, (float*)d_out);
    }
}

// Round 15
// 143.392 us; speedup vs baseline: 1.0837x; 1.0837x over previous
//
#include <hip/hip_runtime.h>
#include <hip/hip_bf16.h>
#include <stdint.h>

typedef __bf16 bf16;
typedef __bf16 bf16x8 __attribute__((ext_vector_type(8)));
typedef __bf16 bf16x4 __attribute__((ext_vector_type(4)));
typedef float  f32x4  __attribute__((ext_vector_type(4)));
typedef float  f32x16 __attribute__((ext_vector_type(16)));
typedef uint32_t u32;

#define MFMA16(a,b,c) __builtin_amdgcn_mfma_f32_16x16x32_bf16((a),(b),(c),0,0,0)
#define MFMA32(a,b,c) __builtin_amdgcn_mfma_f32_32x32x16_bf16((a),(b),(c),0,0,0)

// 0.125 (1/sqrt(64)) * log2(e): folded into Wq/bq so softmax runs in exp2 domain.
#define QSCL 0.1803368801111204f

// ---------- helpers ----------
__device__ __forceinline__ u32 sx32(u32 x) {  // value from lane^32 (HW-verified r3)
    return (u32)__shfl_xor((int)x, 32, 64);
}
__device__ __forceinline__ float swapred_max(float v) {
    return fmaxf(v, __builtin_bit_cast(float, sx32(__builtin_bit_cast(u32, v))));
}
__device__ __forceinline__ float swapred_sum(float v) {
    return v + __builtin_bit_cast(float, sx32(__builtin_bit_cast(u32, v)));
}
__device__ __forceinline__ u32 pkbf(float lo, float hi) {
    union { bf16 h[2]; u32 u; } un;
    un.h[0] = (bf16)lo; un.h[1] = (bf16)hi;
    return un.u;
}
// p[16] = exp'd scores for one 32-row K-block; lane (lm,hi) holds k_local(r) =
// (r&3) + 8*(r>>2) + 4*hi for col q=lm. Produce PV B-frags f0 (k=0..15) and
// f1 (k=16..31): lane needs k = 16*ks + hi*8 + j (j=0..7) at col q=lm.
__device__ __forceinline__ void pack_frags(const float* p, int hi, bf16x8& f0, bf16x8& f1) {
    u32 k01 = pkbf(p[0],  p[1]),  k23 = pkbf(p[2],  p[3]);
    u32 k45 = pkbf(p[4],  p[5]),  k67 = pkbf(p[6],  p[7]);
    u32 k89 = pkbf(p[8],  p[9]),  kab = pkbf(p[10], p[11]);
    u32 kcd = pkbf(p[12], p[13]), kef = pkbf(p[14], p[15]);
    u32 x01 = sx32(k01), x23 = sx32(k23), x45 = sx32(k45), x67 = sx32(k67);
    u32 x89 = sx32(k89), xab = sx32(kab), xcd = sx32(kcd), xef = sx32(kef);
    union { u32 w[4]; bf16x8 v; } u0, u1;
    u0.w[0] = hi ? x45 : k01;  u0.w[1] = hi ? x67 : k23;
    u0.w[2] = hi ? k45 : x01;  u0.w[3] = hi ? k67 : x23;
    u1.w[0] = hi ? xcd : k89;  u1.w[1] = hi ? xef : kab;
    u1.w[2] = hi ? kcd : x89;  u1.w[3] = hi ? kef : xab;
    f0 = u0.v; f1 = u1.v;
}

// ---------------- weight transpose: W[k][n] fp32 -> Wt[n][k] bf16 (* scale) ----------------
__device__ __forceinline__ void transpose_body(const float* __restrict__ W, bf16* __restrict__ Wt,
                                               float scale, int n0, int k0) {
    __shared__ bf16 t[64][65];
    for (int i = 0; i < 16; ++i) {
        int idx = threadIdx.x + i * 256, r = idx >> 6, c = idx & 63;
        t[r][c] = (bf16)(W[(size_t)(k0 + r) * 1024 + n0 + c] * scale);
    }
    __syncthreads();
    for (int i = 0; i < 16; ++i) {
        int idx = threadIdx.x + i * 256, r = idx >> 6, c = idx & 63;
        Wt[(size_t)(n0 + r) * 1024 + k0 + c] = t[c][r];
    }
}
__global__ __launch_bounds__(256) void k_transpose_w(const float* __restrict__ W,
                                                     bf16* __restrict__ Wt, float scale) {
    transpose_body(W, Wt, scale, blockIdx.x * 64, blockIdx.y * 64);
}
// all four weights in one launch (grid 16x16x4)
__global__ __launch_bounds__(256) void k_transpose_w4(const float* __restrict__ Wq, const float* __restrict__ Wk,
                                                      const float* __restrict__ Wv, const float* __restrict__ Wo,
                                                      bf16* __restrict__ Wtq, bf16* __restrict__ Wtk,
                                                      bf16* __restrict__ Wtv, bf16* __restrict__ Wto) {
    int z = blockIdx.z;
    const float* W = (z == 0) ? Wq : (z == 1) ? Wk : (z == 2) ? Wv : Wo;
    bf16* Wt = (z == 0) ? Wtq : (z == 1) ? Wtk : (z == 2) ? Wtv : Wto;
    transpose_body(W, Wt, (z == 0) ? QSCL : 1.0f, blockIdx.x * 64, blockIdx.y * 64);
}

// ---------------- mixed GEMM tile (R11-proven), 128x128, K=1024 ----------------
// One operand fp32 (reg-staged with in-staging bf16 cvt), the other bf16 (glds).
// out_mode 0: bf16 head layout [b][h][s][d]; out_mode 2: bf16 Vt layout [bh][d][s].
template <int A_F32, int B_F32>
__device__ __forceinline__ void gemm_tile2(const void* __restrict__ Ap, const void* __restrict__ Btp,
                                           const float* __restrict__ bias, float bscale,
                                           void* __restrict__ Cp, int out_mode, int m0, int n0,
                                           bf16 (*As)[64], bf16 (*Bs)[64]) {
    const int tid = threadIdx.x;
    const int wid = tid >> 6, lane = tid & 63, lg = lane >> 4, lm = lane & 15;
    const int wr = wid >> 1, wc = wid & 1;
    const int grow = tid >> 3, gcol = (tid & 7) << 3;

    f32x4 acc[4][4] = {};

    for (int kt = 0; kt < 16; ++kt) {
        const int k0 = kt << 6;
        __syncthreads();
#pragma unroll
        for (int p = 0; p < 4; ++p) {
            const int r = p * 32 + grow;
            if constexpr (A_F32) {
                const float* A = (const float*)Ap;
                const float* src = A + (size_t)(m0 + r) * 1024 + k0 + gcol;
                float4 v0 = *(const float4*)src;
                float4 v1 = *(const float4*)(src + 4);
                bf16x8 w = {(bf16)v0.x, (bf16)v0.y, (bf16)v0.z, (bf16)v0.w,
                            (bf16)v1.x, (bf16)v1.y, (bf16)v1.z, (bf16)v1.w};
                *(bf16x8*)&As[r][gcol] = w;
            } else {
                const bf16* A = (const bf16*)Ap;
                __builtin_amdgcn_global_load_lds(
                    (const __attribute__((address_space(1))) void*)(A + (size_t)(m0 + r) * 1024 + k0 + gcol),
                    (__attribute__((address_space(3))) void*)(&As[p * 32 + wid * 8][0]), 16, 0, 0);
            }
            if constexpr (B_F32) {
                const float* B = (const float*)Btp;
                const float* src = B + (size_t)(n0 + r) * 1024 + k0 + gcol;
                float4 v0 = *(const float4*)src;
                float4 v1 = *(const float4*)(src + 4);
                bf16x8 w = {(bf16)v0.x, (bf16)v0.y, (bf16)v0.z, (bf16)v0.w,
                            (bf16)v1.x, (bf16)v1.y, (bf16)v1.z, (bf16)v1.w};
                *(bf16x8*)&Bs[r][gcol] = w;
            } else {
                const bf16* Bt = (const bf16*)Btp;
                __builtin_amdgcn_global_load_lds(
                    (const __attribute__((address_space(1))) void*)(Bt + (size_t)(n0 + r) * 1024 + k0 + gcol),
                    (__attribute__((address_space(3))) void*)(&Bs[p * 32 + wid * 8][0]), 16, 0, 0);
            }
        }
        __syncthreads();
#pragma unroll
        for (int kk = 0; kk < 2; ++kk) {
            bf16x8 a[4], b[4];
#pragma unroll
            for (int i = 0; i < 4; ++i) a[i] = *(const bf16x8*)&As[wr * 64 + i * 16 + lm][kk * 32 + lg * 8];
#pragma unroll
            for (int j = 0; j < 4; ++j) b[j] = *(const bf16x8*)&Bs[wc * 64 + j * 16 + lm][kk * 32 + lg * 8];
#pragma unroll
            for (int i = 0; i < 4; ++i)
#pragma unroll
                for (int j = 0; j < 4; ++j) acc[i][j] = MFMA16(a[i], b[j], acc[i][j]);
        }
    }

    for (int i = 0; i < 4; ++i) {
        for (int j = 0; j < 4; ++j) {
            int col = n0 + wc * 64 + j * 16 + lm;
            for (int q = 0; q < 4; ++q) {
                int row = m0 + wr * 64 + i * 16 + lg * 4 + q;
                if (out_mode == 0) {  // bf16 head layout [b][h][s][d]
                    float val = acc[i][j][q] + bscale * bias[col];
                    int bb = row >> 11, s = row & 2047, h = col >> 6, d = col & 63;
                    ((bf16*)Cp)[(((size_t)bb * 16 + h) * 2048 + s) * 64 + d] = (bf16)val;
                } else {              // Vt layout [bh][d][s], bias per ROW
                    float val = acc[i][j][q] + bias[row];
                    size_t idx = (((size_t)(col >> 11) * 16 + (row >> 6)) * 64 + (row & 63)) * 2048 + (col & 2047);
                    ((bf16*)Cp)[idx] = (bf16)val;
                }
            }
        }
    }
}

// XCD-stripe decode for M=4096,N=1024: xcd owns m-tiles 4*xcd..4*xcd+3.
__device__ __forceinline__ void tile_decode(int r, int& m0, int& n0) {
    int xcd = r & 7, slot = (r >> 3) & 3, n = (r >> 5) & 7;
    m0 = (xcd * 4 + slot) * 128;
    n0 = n * 128;
}
// decode for Vt gemm (M=1024 weight-rows, N=4096 seq): xcd owns 4 n-tiles.
__device__ __forceinline__ void tile_decode_vt(int r, int& m0, int& n0) {
    int xcd = r & 7, loc = r >> 3;       // loc in [0,32)
    int nslot = loc & 3, m = loc >> 2;   // m in [0,8)
    n0 = (xcd * 4 + nslot) * 128;
    m0 = m * 128;
}

// Q/K projection (A = fp32 activation, Bt = bf16 weight)
__global__ __launch_bounds__(256, 4) void k_gemm_proj(const float* __restrict__ A,
                                                      const bf16* __restrict__ Bt,
                                                      const float* __restrict__ bias, float bscale,
                                                      void* __restrict__ Cp) {
    __shared__ bf16 As[128][64];
    __shared__ bf16 Bs[128][64];
    int m0, n0;
    tile_decode(blockIdx.x, m0, n0);
    gemm_tile2<1, 0>((const void*)A, (const void*)Bt, bias, bscale, Cp, 0, m0, n0, As, Bs);
}

// V projection producing Vt directly (A = bf16 weight, Bt = fp32 activation)
__global__ __launch_bounds__(256, 4) void k_gemm_vt(const bf16* __restrict__ Wtv,
                                                    const float* __restrict__ v,
                                                    const float* __restrict__ bias,
                                                    bf16* __restrict__ Vtb) {
    __shared__ bf16 As[128][64];
    __shared__ bf16 Bs[128][64];
    int m0, n0;
    tile_decode_vt(blockIdx.x, m0, n0);
    gemm_tile2<0, 1>((const void*)Wtv, (const void*)v, bias, 1.0f, (void*)Vtb, 2, m0, n0, As, Bs);
}

// fused Q/K/V projections with in-staging fp32->bf16 cvt: grid 768 (3 blocks/CU)
__global__ __launch_bounds__(256, 4) void k_gemm_qkv(const float* __restrict__ q, const float* __restrict__ k,
                                                     const float* __restrict__ v,
                                                     const bf16* __restrict__ Wtq, const bf16* __restrict__ Wtk,
                                                     const bf16* __restrict__ Wtv,
                                                     const float* __restrict__ bq, const float* __restrict__ bk,
                                                     const float* __restrict__ bv,
                                                     bf16* __restrict__ Qb, bf16* __restrict__ Kb,
                                                     bf16* __restrict__ Vtb) {
    __shared__ bf16 As[128][64];
    __shared__ bf16 Bs[128][64];
    int l = blockIdx.x, z = l >> 8, r = l & 255;
    int m0, n0;
    if (z == 2) {
        tile_decode_vt(r, m0, n0);
        // A = bf16 weight Wtv, Bt = fp32 activation v (order matters! R14 bug was a swap)
        gemm_tile2<0, 1>((const void*)Wtv, (const void*)v, bv, 1.0f, (void*)Vtb, 2, m0, n0, As, Bs);
    } else {
        tile_decode(r, m0, n0);
        const float* A  = (z == 0) ? q : k;
        const bf16* Bt  = (z == 0) ? Wtq : Wtk;
        const float* bias = (z == 0) ? bq : bk;
        float bscale = (z == 0) ? QSCL : 1.0f;
        bf16* Cp = (z == 0) ? Qb : Kb;
        gemm_tile2<1, 0>((const void*)A, (const void*)Bt, bias, bscale, (void*)Cp, 0, m0, n0, As, Bs);
    }
}

// ---------------- output projection: 128x64 tiles, 512 blocks (2/CU) ----------------
__global__ __launch_bounds__(256, 4) void k_gemm_out(const bf16* __restrict__ A,
                                                     const bf16* __restrict__ Bt,
                                                     const float* __restrict__ bias,
                                                     float* __restrict__ C) {
    __shared__ bf16 As[128][64];
    __shared__ bf16 Bs[64][64];
    const int tid = threadIdx.x;
    const int wid = tid >> 6, lane = tid & 63, lg = lane >> 4, lm = lane & 15;
    const int grow = tid >> 3, gcol = (tid & 7) << 3;
    const int r = blockIdx.x;
    const int xcd = r & 7, loc = r >> 3;
    const int mslot = loc & 3, n = loc >> 2;
    const int m0 = (xcd * 4 + mslot) * 128, n0 = n * 64;

    f32x4 acc[2][4] = {};

    for (int kt = 0; kt < 16; ++kt) {
        const int k0 = kt << 6;
        __syncthreads();
#pragma unroll
        for (int p = 0; p < 4; ++p)
            __builtin_amdgcn_global_load_lds(
                (const __attribute__((address_space(1))) void*)(A + (size_t)(m0 + p * 32 + grow) * 1024 + k0 + gcol),
                (__attribute__((address_space(3))) void*)(&As[p * 32 + wid * 8][0]), 16, 0, 0);
#pragma unroll
        for (int p = 0; p < 2; ++p)
            __builtin_amdgcn_global_load_lds(
                (const __attribute__((address_space(1))) void*)(Bt + (size_t)(n0 + p * 32 + grow) * 1024 + k0 + gcol),
                (__attribute__((address_space(3))) void*)(&Bs[p * 32 + wid * 8][0]), 16, 0, 0);
        __syncthreads();
#pragma unroll
        for (int kk = 0; kk < 2; ++kk) {
            bf16x8 a[2], b[4];
#pragma unroll
            for (int i = 0; i < 2; ++i) a[i] = *(const bf16x8*)&As[wid * 32 + i * 16 + lm][kk * 32 + lg * 8];
#pragma unroll
            for (int j = 0; j < 4; ++j) b[j] = *(const bf16x8*)&Bs[j * 16 + lm][kk * 32 + lg * 8];
#pragma unroll
            for (int i = 0; i < 2; ++i)
#pragma unroll
                for (int j = 0; j < 4; ++j) acc[i][j] = MFMA16(a[i], b[j], acc[i][j]);
        }
    }

    for (int i = 0; i < 2; ++i) {
        for (int j = 0; j < 4; ++j) {
            int col = n0 + j * 16 + lm;
            float bv = bias[col];
            for (int q = 0; q < 4; ++q) {
                int row = m0 + wid * 32 + i * 16 + lg * 4 + q;
                C[(size_t)row * 1024 + col] = acc[i][j][q] + bv;
            }
        }
    }
}

// ---------------- flash attention: 8-wave LDS-staged + DEFERRED PV pipeline ----------------
// PV of tile kt-1 issues right after QK of tile kt (independent register operands
// vfp/pfp) so the matrix pipe runs PV while the VALU does softmax(kt).
// Bit-identical math: PV(t) still lands in O before any rescale at t+1 (program order).
// Q,K: [bh][2048][64] bf16 (Q pre-scaled); Vt: [bh][64][2048]; Out: [b][s][h*64+d] bf16.
__global__ __launch_bounds__(512, 2) void k_attn(const bf16* __restrict__ Q,
                                                 const bf16* __restrict__ Kb,
                                                 const bf16* __restrict__ Vt,
                                                 bf16* __restrict__ Out) {
    __shared__ bf16 Ks[2][64 * 64];
    __shared__ bf16 Vs[2][64 * 64];
    const int tid = threadIdx.x;
    const int wid = tid >> 6, lane = tid & 63;
    const int lm = lane & 31, hi = lane >> 5;
    const int bid = blockIdx.x;
    const int bh = bid & 31, qt = bid >> 5;   // same-bh blocks share an XCD's L2
    const int bb = bh >> 4, h = bh & 15;
    const int qrow = qt * 256 + wid * 32 + lm;
    const size_t qk_base = (size_t)bh * (2048 * 64);
    const size_t vt_base = (size_t)bh * (64 * 2048);

    // staging geometry (proven r6): LDS[row][c] = global[row][c ^ (row&7)] via source swizzle
    const int srow = tid >> 3, sc8 = tid & 7;
    const int cse = (sc8 ^ (srow & 7)) * 8;
    const bf16* kstage = Kb + qk_base + (size_t)srow * 64 + cse;     // + kt*4096
    const bf16* vstage = Vt + vt_base + (size_t)srow * 2048 + cse;   // + kt*64
    const int ldsoff = wid * 1024;

    bf16x8 qf[4];
    {
        const bf16* qp = Q + qk_base + (size_t)qrow * 64 + hi * 8;
#pragma unroll
        for (int f = 0; f < 4; ++f) qf[f] = *(const bf16x8*)(qp + f * 16);
    }

    f32x16 O0 = {}, O1 = {};
    float mrow = -1e30f, lsum = 0.f;   // lsum = this lane's half; cross-half sum deferred

    const int swz = (lm & 7);

    __builtin_amdgcn_global_load_lds(
        (const __attribute__((address_space(1))) void*)(kstage),
        (__attribute__((address_space(3))) void*)((char*)&Ks[0][0] + ldsoff), 16, 0, 0);
    __builtin_amdgcn_global_load_lds(
        (const __attribute__((address_space(1))) void*)(vstage),
        (__attribute__((address_space(3))) void*)((char*)&Vs[0][0] + ldsoff), 16, 0, 0);
    __syncthreads();

    bf16x8 pfp[4];            // P frags of tile kt-1 (deferred PV operand)
    bf16x8 vfp0[4], vfp1[4];  // V frags of tile kt-1

    int cur = 0;
#pragma unroll 1
    for (int kt = 0; kt < 32; ++kt) {
        if (kt + 1 < 32) {
            __builtin_amdgcn_global_load_lds(
                (const __attribute__((address_space(1))) void*)(kstage + (size_t)(kt + 1) * 4096),
                (__attribute__((address_space(3))) void*)((char*)&Ks[cur ^ 1][0] + ldsoff), 16, 0, 0);
            __builtin_amdgcn_global_load_lds(
                (const __attribute__((address_space(1))) void*)(vstage + (size_t)(kt + 1) * 64),
                (__attribute__((address_space(3))) void*)((char*)&Vs[cur ^ 1][0] + ldsoff), 16, 0, 0);
        }

        const char* Ksc = (const char*)&Ks[cur][0];
        const char* Vsc = (const char*)&Vs[cur][0];

        bf16x8 kf0[4], kf1[4];
#pragma unroll
        for (int f = 0; f < 4; ++f) {
            int ch = (f << 1) | hi;
            kf0[f] = *(const bf16x8*)(Ksc + lm * 128 + ((ch ^ swz) << 4));
            kf1[f] = *(const bf16x8*)(Ksc + (lm + 32) * 128 + ((ch ^ swz) << 4));
        }

        // S^T = K · Q^T  (tile kt)
        f32x16 s0 = {}, s1 = {};
#pragma unroll
        for (int f = 0; f < 4; ++f) {
            s0 = MFMA32(kf0[f], qf[f], s0);
            s1 = MFMA32(kf1[f], qf[f], s1);
        }

        // deferred PV of tile kt-1: independent of s0/s1 — keeps the matrix pipe
        // busy while the softmax below waits on the QK results.
        if (kt > 0) {
#pragma unroll
            for (int ks = 0; ks < 4; ++ks) {
                O0 = MFMA32(vfp0[ks], pfp[ks], O0);
                O1 = MFMA32(vfp1[ks], pfp[ks], O1);
            }
        }

        // V frags of tile kt -> vfp (consumed next iteration / epilogue)
#pragma unroll
        for (int ks = 0; ks < 4; ++ks) {
            int ch = (ks << 1) | hi;
            vfp0[ks] = *(const bf16x8*)(Vsc + lm * 128 + ((ch ^ swz) << 4));
            vfp1[ks] = *(const bf16x8*)(Vsc + (lm + 32) * 128 + ((ch ^ swz) << 4));
        }

        // speculative P = exp2(S - mrow_old): overlaps the max reduction
        float pe0[16], pe1[16];
#pragma unroll
        for (int r = 0; r < 16; ++r) pe0[r] = __builtin_amdgcn_exp2f(s0[r] - mrow);
#pragma unroll
        for (int r = 0; r < 16; ++r) pe1[r] = __builtin_amdgcn_exp2f(s1[r] - mrow);

        // tile row-max (tree + cross-half swap)
        float t8[8];
#pragma unroll
        for (int r = 0; r < 8; ++r)
            t8[r] = fmaxf(fmaxf(s0[r], s0[r + 8]), fmaxf(s1[r], s1[r + 8]));
#pragma unroll
        for (int st = 4; st; st >>= 1)
#pragma unroll
            for (int r = 0; r < st; ++r) t8[r] = fmaxf(t8[r], t8[r + st]);
        float pm = swapred_max(t8[0]);

        // defer-max: rescale only when max grew > 8. O already contains PV(0..kt-1)
        // at scale m_old (the deferred PV above ran first), so scales stay matched.
        if (!__all(pm <= mrow + 8.0f)) {
            float mnew = fmaxf(mrow, pm);
            float corr = __builtin_amdgcn_exp2f(mrow - mnew);
            lsum *= corr;
            O0 *= corr;
            O1 *= corr;
            mrow = mnew;
#pragma unroll
            for (int r = 0; r < 16; ++r) pe0[r] = __builtin_amdgcn_exp2f(s0[r] - mrow);
#pragma unroll
            for (int r = 0; r < 16; ++r) pe1[r] = __builtin_amdgcn_exp2f(s1[r] - mrow);
        }

        // lane-local row-sum (cross-half swap deferred to epilogue)
        float u8[8];
#pragma unroll
        for (int r = 0; r < 8; ++r) u8[r] = (pe0[r] + pe0[r + 8]) + (pe1[r] + pe1[r + 8]);
#pragma unroll
        for (int st = 4; st; st >>= 1)
#pragma unroll
            for (int r = 0; r < st; ++r) u8[r] = u8[r] + u8[r + st];
        lsum += u8[0];

        // redistribute P into PV B-frags for the NEXT iteration
        pack_frags(pe0, hi, pfp[0], pfp[1]);
        pack_frags(pe1, hi, pfp[2], pfp[3]);

        __syncthreads();
        cur ^= 1;
    }

    // epilogue: PV of the last tile
#pragma unroll
    for (int ks = 0; ks < 4; ++ks) {
        O0 = MFMA32(vfp0[ks], pfp[ks], O0);
        O1 = MFMA32(vfp1[ks], pfp[ks], O1);
    }

    float lrow = swapred_sum(lsum);
    float inv = 1.0f / lrow;
    bf16* op = Out + ((size_t)bb * 2048 + qrow) * 1024 + h * 64 + 4 * hi;
#pragma unroll
    for (int t = 0; t < 4; ++t) {
        bf16x4 w0, w1;
#pragma unroll
        for (int e = 0; e < 4; ++e) {
            w0[e] = (bf16)(O0[4 * t + e] * inv);
            w1[e] = (bf16)(O1[4 * t + e] * inv);
        }
        *(bf16x4*)(op + 8 * t)      = w0;   // d = 4*hi + 8*t + e
        *(bf16x4*)(op + 32 + 8 * t) = w1;   // + 32
    }
}

extern "C" void kernel_launch(void* const* d_in, const int* in_sizes, int n_in,
                              void* d_out, int out_size, void* d_ws, size_t ws_size,
                              hipStream_t stream) {
    const float* q  = (const float*)d_in[0];
    const float* k  = (const float*)d_in[1];
    const float* v  = (const float*)d_in[2];
    const float* Wq = (const float*)d_in[3];
    const float* bq = (const float*)d_in[4];
    const float* Wk = (const float*)d_in[5];
    const float* bk = (const float*)d_in[6];
    const float* Wv = (const float*)d_in[7];
    const float* bv = (const float*)d_in[8];
    const float* Wo = (const float*)d_in[9];
    const float* bo = (const float*)d_in[10];

    char* ws = (char*)d_ws;
    const size_t MB = 1ull << 20;
    const dim3 twg(16, 16), blk(256);

    if (ws_size >= 40 * MB) {
        // fused path (40 MB): no cvt pass, no combine (R11-proven)
        bf16* Wtq = (bf16*)(ws + 0 * MB);
        bf16* Wtk = (bf16*)(ws + 2 * MB);
        bf16* Wtv = (bf16*)(ws + 4 * MB);
        bf16* Wto = (bf16*)(ws + 6 * MB);
        bf16* Qb  = (bf16*)(ws + 8 * MB);
        bf16* Kb  = (bf16*)(ws + 16 * MB);
        bf16* Vtb = (bf16*)(ws + 24 * MB);
        bf16* AOb = (bf16*)(ws + 32 * MB);

        k_transpose_w4<<<dim3(16, 16, 4), blk, 0, stream>>>(Wq, Wk, Wv, Wo, Wtq, Wtk, Wtv, Wto);
        k_gemm_qkv<<<768, blk, 0, stream>>>(q, k, v, Wtq, Wtk, Wtv, bq, bk, bv, Qb, Kb, Vtb);
        k_attn<<<256, 512, 0, stream>>>(Qb, Kb, Vtb, AOb);
        k_gemm_out<<<512, blk, 0, stream>>>(AOb, Wto, bo, (float*)d_out);
    } else {
        // sequential fallback (34 MB ws)
        bf16* Wt   = (bf16*)(ws + 0 * MB);
        bf16* Qb   = (bf16*)(ws + 2 * MB);
        bf16* Kb   = (bf16*)(ws + 10 * MB);
        bf16* Vtb  = (bf16*)(ws + 18 * MB);
        bf16* AOb  = (bf16*)(ws + 26 * MB);

        k_transpose_w<<<twg, blk, 0, stream>>>(Wq, Wt, QSCL);
        k_gemm_proj<<<256, blk, 0, stream>>>(q, Wt, bq, QSCL, (void*)Qb);
        k_transpose_w<<<twg, blk, 0, stream>>>(Wk, Wt, 1.0f);
        k_gemm_proj<<<256, blk, 0, stream>>>(k, Wt, bk, 1.0f, (void*)Kb);
        k_transpose_w<<<twg, blk, 0, stream>>>(Wv, Wt, 1.0f);
        k_gemm_vt<<<256, blk, 0, stream>>>(Wt, v, bv, Vtb);
        k_transpose_w<<<twg, blk, 0, stream>>>(Wo, Wt, 1.0f);
        k_attn<<<256, 512, 0, stream>>>(Qb, Kb, Vtb, AOb);
        k_gemm_out<<<512, blk, 0, stream>>>(AOb, Wt, bo, (float*)d_out);
    }
}

// Round 16
// 138.009 us; speedup vs baseline: 1.1259x; 1.0390x over previous
//
#include <hip/hip_runtime.h>
#include <hip/hip_bf16.h>
#include <stdint.h>

typedef __bf16 bf16;
typedef __bf16 bf16x8 __attribute__((ext_vector_type(8)));
typedef __bf16 bf16x4 __attribute__((ext_vector_type(4)));
typedef float  f32x4  __attribute__((ext_vector_type(4)));
typedef float  f32x16 __attribute__((ext_vector_type(16)));
typedef uint32_t u32;

#define MFMA16(a,b,c) __builtin_amdgcn_mfma_f32_16x16x32_bf16((a),(b),(c),0,0,0)
#define MFMA32(a,b,c) __builtin_amdgcn_mfma_f32_32x32x16_bf16((a),(b),(c),0,0,0)

// 0.125 (1/sqrt(64)) * log2(e): folded into Wq/bq so softmax runs in exp2 domain.
#define QSCL 0.1803368801111204f

// ---------- helpers ----------
__device__ __forceinline__ u32 sx32(u32 x) {  // value from lane^32 (HW-verified r3)
    return (u32)__shfl_xor((int)x, 32, 64);
}
__device__ __forceinline__ float swapred_max(float v) {
    return fmaxf(v, __builtin_bit_cast(float, sx32(__builtin_bit_cast(u32, v))));
}
__device__ __forceinline__ float swapred_sum(float v) {
    return v + __builtin_bit_cast(float, sx32(__builtin_bit_cast(u32, v)));
}
__device__ __forceinline__ u32 pkbf(float lo, float hi) {
    union { bf16 h[2]; u32 u; } un;
    un.h[0] = (bf16)lo; un.h[1] = (bf16)hi;
    return un.u;
}
// p[16] = exp'd scores for one 32-row K-block; lane (lm,hi) holds k_local(r) =
// (r&3) + 8*(r>>2) + 4*hi for col q=lm. Produce PV B-frags f0 (k=0..15) and
// f1 (k=16..31): lane needs k = 16*ks + hi*8 + j (j=0..7) at col q=lm.
__device__ __forceinline__ void pack_frags(const float* p, int hi, bf16x8& f0, bf16x8& f1) {
    u32 k01 = pkbf(p[0],  p[1]),  k23 = pkbf(p[2],  p[3]);
    u32 k45 = pkbf(p[4],  p[5]),  k67 = pkbf(p[6],  p[7]);
    u32 k89 = pkbf(p[8],  p[9]),  kab = pkbf(p[10], p[11]);
    u32 kcd = pkbf(p[12], p[13]), kef = pkbf(p[14], p[15]);
    u32 x01 = sx32(k01), x23 = sx32(k23), x45 = sx32(k45), x67 = sx32(k67);
    u32 x89 = sx32(k89), xab = sx32(kab), xcd = sx32(kcd), xef = sx32(kef);
    union { u32 w[4]; bf16x8 v; } u0, u1;
    u0.w[0] = hi ? x45 : k01;  u0.w[1] = hi ? x67 : k23;
    u0.w[2] = hi ? k45 : x01;  u0.w[3] = hi ? k67 : x23;
    u1.w[0] = hi ? xcd : k89;  u1.w[1] = hi ? xef : kab;
    u1.w[2] = hi ? kcd : x89;  u1.w[3] = hi ? kef : xab;
    f0 = u0.v; f1 = u1.v;
}

// ---------------- weight transpose: W[k][n] fp32 -> Wt[n][k] bf16 (* scale) ----------------
__device__ __forceinline__ void transpose_body(const float* __restrict__ W, bf16* __restrict__ Wt,
                                               float scale, int n0, int k0) {
    __shared__ bf16 t[64][65];
    for (int i = 0; i < 16; ++i) {
        int idx = threadIdx.x + i * 256, r = idx >> 6, c = idx & 63;
        t[r][c] = (bf16)(W[(size_t)(k0 + r) * 1024 + n0 + c] * scale);
    }
    __syncthreads();
    for (int i = 0; i < 16; ++i) {
        int idx = threadIdx.x + i * 256, r = idx >> 6, c = idx & 63;
        Wt[(size_t)(n0 + r) * 1024 + k0 + c] = t[c][r];
    }
}
__global__ __launch_bounds__(256) void k_transpose_w(const float* __restrict__ W,
                                                     bf16* __restrict__ Wt, float scale) {
    transpose_body(W, Wt, scale, blockIdx.x * 64, blockIdx.y * 64);
}
// all four weights in one launch (grid 16x16x4)
__global__ __launch_bounds__(256) void k_transpose_w4(const float* __restrict__ Wq, const float* __restrict__ Wk,
                                                      const float* __restrict__ Wv, const float* __restrict__ Wo,
                                                      bf16* __restrict__ Wtq, bf16* __restrict__ Wtk,
                                                      bf16* __restrict__ Wtv, bf16* __restrict__ Wto) {
    int z = blockIdx.z;
    const float* W = (z == 0) ? Wq : (z == 1) ? Wk : (z == 2) ? Wv : Wo;
    bf16* Wt = (z == 0) ? Wtq : (z == 1) ? Wtk : (z == 2) ? Wtv : Wto;
    transpose_body(W, Wt, (z == 0) ? QSCL : 1.0f, blockIdx.x * 64, blockIdx.y * 64);
}

// ---------------- mixed GEMM tile, 128x128, K=1024, issue-early fp32 prefetch ----------------
// One operand fp32 (reg-prefetched one K-step ahead; cvt+ds_write in the staging
// phase), the other bf16 (glds). Single 32KB LDS pair (occupancy preserved vs R12).
// Per K-step: [barrier] write32(kt)+glds(kt) [barrier] issue32(kt+1) MFMAs(kt).
// The fp32 loads land under the MFMAs; the cvt's implicit waitcnt finds them ready.
// out_mode 0: bf16 head layout [b][h][s][d]; out_mode 2: bf16 Vt layout [bh][d][s].
template <int A_F32, int B_F32>
__device__ __forceinline__ void gemm_tile2(const void* __restrict__ Ap, const void* __restrict__ Btp,
                                           const float* __restrict__ bias, float bscale,
                                           void* __restrict__ Cp, int out_mode, int m0, int n0,
                                           bf16 (*As)[64], bf16 (*Bs)[64]) {
    const int tid = threadIdx.x;
    const int wid = tid >> 6, lane = tid & 63, lg = lane >> 4, lm = lane & 15;
    const int wr = wid >> 1, wc = wid & 1;
    const int grow = tid >> 3, gcol = (tid & 7) << 3;
    const int r32base = A_F32 ? m0 : n0;   // row base of the fp32 operand
    const int r16base = A_F32 ? n0 : m0;   // row base of the bf16 operand

    f32x4 acc[4][4] = {};
    float4 rA[4][2];   // fp32 prefetch registers (one K-step ahead)

    auto issue32 = [&](int kt) {
        const float* P32 = A_F32 ? (const float*)Ap : (const float*)Btp;
#pragma unroll
        for (int p = 0; p < 4; ++p) {
            const float* src = P32 + (size_t)(r32base + p * 32 + grow) * 1024 + (kt << 6) + gcol;
            rA[p][0] = *(const float4*)src;
            rA[p][1] = *(const float4*)(src + 4);
        }
    };
    auto write32 = [&]() {
#pragma unroll
        for (int p = 0; p < 4; ++p) {
            bf16x8 w = {(bf16)rA[p][0].x, (bf16)rA[p][0].y, (bf16)rA[p][0].z, (bf16)rA[p][0].w,
                        (bf16)rA[p][1].x, (bf16)rA[p][1].y, (bf16)rA[p][1].z, (bf16)rA[p][1].w};
            if constexpr (A_F32) *(bf16x8*)&As[p * 32 + grow][gcol] = w;
            else                 *(bf16x8*)&Bs[p * 32 + grow][gcol] = w;
        }
    };
    auto stage16 = [&](int kt) {
        const bf16* P16 = A_F32 ? (const bf16*)Btp : (const bf16*)Ap;
#pragma unroll
        for (int p = 0; p < 4; ++p) {
            bf16* dst = A_F32 ? &Bs[p * 32 + wid * 8][0] : &As[p * 32 + wid * 8][0];
            __builtin_amdgcn_global_load_lds(
                (const __attribute__((address_space(1))) void*)(P16 + (size_t)(r16base + p * 32 + grow) * 1024 + (kt << 6) + gcol),
                (__attribute__((address_space(3))) void*)dst, 16, 0, 0);
        }
    };

    issue32(0);   // prologue prefetch

#pragma unroll 1
    for (int kt = 0; kt < 16; ++kt) {
        __syncthreads();        // prior-iteration LDS reads complete
        write32();              // cvt + ds_write tile kt (regs landed during prior compute)
        stage16(kt);            // glds bf16 operand tile kt
        __syncthreads();        // LDS ready (drains glds + ds_write)
        if (kt < 15) issue32(kt + 1);   // fp32 loads fly under the MFMAs below
#pragma unroll
        for (int kk = 0; kk < 2; ++kk) {
            bf16x8 a[4], b[4];
#pragma unroll
            for (int i = 0; i < 4; ++i) a[i] = *(const bf16x8*)&As[wr * 64 + i * 16 + lm][kk * 32 + lg * 8];
#pragma unroll
            for (int j = 0; j < 4; ++j) b[j] = *(const bf16x8*)&Bs[wc * 64 + j * 16 + lm][kk * 32 + lg * 8];
#pragma unroll
            for (int i = 0; i < 4; ++i)
#pragma unroll
                for (int j = 0; j < 4; ++j) acc[i][j] = MFMA16(a[i], b[j], acc[i][j]);
        }
    }

    for (int i = 0; i < 4; ++i) {
        for (int j = 0; j < 4; ++j) {
            int col = n0 + wc * 64 + j * 16 + lm;
            for (int q = 0; q < 4; ++q) {
                int row = m0 + wr * 64 + i * 16 + lg * 4 + q;
                if (out_mode == 0) {  // bf16 head layout [b][h][s][d]
                    float val = acc[i][j][q] + bscale * bias[col];
                    int bb = row >> 11, s = row & 2047, h = col >> 6, d = col & 63;
                    ((bf16*)Cp)[(((size_t)bb * 16 + h) * 2048 + s) * 64 + d] = (bf16)val;
                } else {              // Vt layout [bh][d][s], bias per ROW
                    float val = acc[i][j][q] + bias[row];
                    size_t idx = (((size_t)(col >> 11) * 16 + (row >> 6)) * 64 + (row & 63)) * 2048 + (col & 2047);
                    ((bf16*)Cp)[idx] = (bf16)val;
                }
            }
        }
    }
}

// XCD-stripe decode for M=4096,N=1024: xcd owns m-tiles 4*xcd..4*xcd+3.
__device__ __forceinline__ void tile_decode(int r, int& m0, int& n0) {
    int xcd = r & 7, slot = (r >> 3) & 3, n = (r >> 5) & 7;
    m0 = (xcd * 4 + slot) * 128;
    n0 = n * 128;
}
// decode for Vt gemm (M=1024 weight-rows, N=4096 seq): xcd owns 4 n-tiles.
__device__ __forceinline__ void tile_decode_vt(int r, int& m0, int& n0) {
    int xcd = r & 7, loc = r >> 3;       // loc in [0,32)
    int nslot = loc & 3, m = loc >> 2;   // m in [0,8)
    n0 = (xcd * 4 + nslot) * 128;
    m0 = m * 128;
}

// Q/K projection (A = fp32 activation, Bt = bf16 weight)
__global__ __launch_bounds__(256, 4) void k_gemm_proj(const float* __restrict__ A,
                                                      const bf16* __restrict__ Bt,
                                                      const float* __restrict__ bias, float bscale,
                                                      void* __restrict__ Cp) {
    __shared__ bf16 As[128][64];
    __shared__ bf16 Bs[128][64];
    int m0, n0;
    tile_decode(blockIdx.x, m0, n0);
    gemm_tile2<1, 0>((const void*)A, (const void*)Bt, bias, bscale, Cp, 0, m0, n0, As, Bs);
}

// V projection producing Vt directly (A = bf16 weight, Bt = fp32 activation)
__global__ __launch_bounds__(256, 4) void k_gemm_vt(const bf16* __restrict__ Wtv,
                                                    const float* __restrict__ v,
                                                    const float* __restrict__ bias,
                                                    bf16* __restrict__ Vtb) {
    __shared__ bf16 As[128][64];
    __shared__ bf16 Bs[128][64];
    int m0, n0;
    tile_decode_vt(blockIdx.x, m0, n0);
    gemm_tile2<0, 1>((const void*)Wtv, (const void*)v, bias, 1.0f, (void*)Vtb, 2, m0, n0, As, Bs);
}

// fused Q/K/V projections with in-staging fp32->bf16 cvt: grid 768 (3 blocks/CU)
__global__ __launch_bounds__(256, 4) void k_gemm_qkv(const float* __restrict__ q, const float* __restrict__ k,
                                                     const float* __restrict__ v,
                                                     const bf16* __restrict__ Wtq, const bf16* __restrict__ Wtk,
                                                     const bf16* __restrict__ Wtv,
                                                     const float* __restrict__ bq, const float* __restrict__ bk,
                                                     const float* __restrict__ bv,
                                                     bf16* __restrict__ Qb, bf16* __restrict__ Kb,
                                                     bf16* __restrict__ Vtb) {
    __shared__ bf16 As[128][64];
    __shared__ bf16 Bs[128][64];
    int l = blockIdx.x, z = l >> 8, r = l & 255;
    int m0, n0;
    if (z == 2) {
        tile_decode_vt(r, m0, n0);
        // A = bf16 weight Wtv, Bt = fp32 activation v (order matters! R14 bug was a swap)
        gemm_tile2<0, 1>((const void*)Wtv, (const void*)v, bv, 1.0f, (void*)Vtb, 2, m0, n0, As, Bs);
    } else {
        tile_decode(r, m0, n0);
        const float* A  = (z == 0) ? q : k;
        const bf16* Bt  = (z == 0) ? Wtq : Wtk;
        const float* bias = (z == 0) ? bq : bk;
        float bscale = (z == 0) ? QSCL : 1.0f;
        bf16* Cp = (z == 0) ? Qb : Kb;
        gemm_tile2<1, 0>((const void*)A, (const void*)Bt, bias, bscale, (void*)Cp, 0, m0, n0, As, Bs);
    }
}

// ---------------- output projection: 128x64 tiles, 512 blocks (2/CU) ----------------
__global__ __launch_bounds__(256, 4) void k_gemm_out(const bf16* __restrict__ A,
                                                     const bf16* __restrict__ Bt,
                                                     const float* __restrict__ bias,
                                                     float* __restrict__ C) {
    __shared__ bf16 As[128][64];
    __shared__ bf16 Bs[64][64];
    const int tid = threadIdx.x;
    const int wid = tid >> 6, lane = tid & 63, lg = lane >> 4, lm = lane & 15;
    const int grow = tid >> 3, gcol = (tid & 7) << 3;
    const int r = blockIdx.x;
    const int xcd = r & 7, loc = r >> 3;
    const int mslot = loc & 3, n = loc >> 2;
    const int m0 = (xcd * 4 + mslot) * 128, n0 = n * 64;

    f32x4 acc[2][4] = {};

    for (int kt = 0; kt < 16; ++kt) {
        const int k0 = kt << 6;
        __syncthreads();
#pragma unroll
        for (int p = 0; p < 4; ++p)
            __builtin_amdgcn_global_load_lds(
                (const __attribute__((address_space(1))) void*)(A + (size_t)(m0 + p * 32 + grow) * 1024 + k0 + gcol),
                (__attribute__((address_space(3))) void*)(&As[p * 32 + wid * 8][0]), 16, 0, 0);
#pragma unroll
        for (int p = 0; p < 2; ++p)
            __builtin_amdgcn_global_load_lds(
                (const __attribute__((address_space(1))) void*)(Bt + (size_t)(n0 + p * 32 + grow) * 1024 + k0 + gcol),
                (__attribute__((address_space(3))) void*)(&Bs[p * 32 + wid * 8][0]), 16, 0, 0);
        __syncthreads();
#pragma unroll
        for (int kk = 0; kk < 2; ++kk) {
            bf16x8 a[2], b[4];
#pragma unroll
            for (int i = 0; i < 2; ++i) a[i] = *(const bf16x8*)&As[wid * 32 + i * 16 + lm][kk * 32 + lg * 8];
#pragma unroll
            for (int j = 0; j < 4; ++j) b[j] = *(const bf16x8*)&Bs[j * 16 + lm][kk * 32 + lg * 8];
#pragma unroll
            for (int i = 0; i < 2; ++i)
#pragma unroll
                for (int j = 0; j < 4; ++j) acc[i][j] = MFMA16(a[i], b[j], acc[i][j]);
        }
    }

    for (int i = 0; i < 2; ++i) {
        for (int j = 0; j < 4; ++j) {
            int col = n0 + j * 16 + lm;
            float bv = bias[col];
            for (int q = 0; q < 4; ++q) {
                int row = m0 + wid * 32 + i * 16 + lg * 4 + q;
                C[(size_t)row * 1024 + col] = acc[i][j][q] + bv;
            }
        }
    }
}

// ---------------- flash attention: 8-wave block, LDS-staged K/V (R11-proven, 69.4 us) ----------------
// Speculative exp (overlaps max-tree latency) + deferred cross-half l-sum; direct
// normalized output write.
// Q,K: [bh][2048][64] bf16 (Q pre-scaled); Vt: [bh][64][2048]; Out: [b][s][h*64+d] bf16.
__global__ __launch_bounds__(512, 2) void k_attn(const bf16* __restrict__ Q,
                                                 const bf16* __restrict__ Kb,
                                                 const bf16* __restrict__ Vt,
                                                 bf16* __restrict__ Out) {
    __shared__ bf16 Ks[2][64 * 64];
    __shared__ bf16 Vs[2][64 * 64];
    const int tid = threadIdx.x;
    const int wid = tid >> 6, lane = tid & 63;
    const int lm = lane & 31, hi = lane >> 5;
    const int bid = blockIdx.x;
    const int bh = bid & 31, qt = bid >> 5;   // same-bh blocks share an XCD's L2
    const int bb = bh >> 4, h = bh & 15;
    const int qrow = qt * 256 + wid * 32 + lm;
    const size_t qk_base = (size_t)bh * (2048 * 64);
    const size_t vt_base = (size_t)bh * (64 * 2048);

    // staging geometry (proven r6): LDS[row][c] = global[row][c ^ (row&7)] via source swizzle
    const int srow = tid >> 3, sc8 = tid & 7;
    const int cse = (sc8 ^ (srow & 7)) * 8;
    const bf16* kstage = Kb + qk_base + (size_t)srow * 64 + cse;     // + kt*4096
    const bf16* vstage = Vt + vt_base + (size_t)srow * 2048 + cse;   // + kt*64
    const int ldsoff = wid * 1024;

    bf16x8 qf[4];
    {
        const bf16* qp = Q + qk_base + (size_t)qrow * 64 + hi * 8;
#pragma unroll
        for (int f = 0; f < 4; ++f) qf[f] = *(const bf16x8*)(qp + f * 16);
    }

    f32x16 O0 = {}, O1 = {};
    float mrow = -1e30f, lsum = 0.f;   // lsum = this lane's half; cross-half sum deferred

    const int swz = (lm & 7);

    __builtin_amdgcn_global_load_lds(
        (const __attribute__((address_space(1))) void*)(kstage),
        (__attribute__((address_space(3))) void*)((char*)&Ks[0][0] + ldsoff), 16, 0, 0);
    __builtin_amdgcn_global_load_lds(
        (const __attribute__((address_space(1))) void*)(vstage),
        (__attribute__((address_space(3))) void*)((char*)&Vs[0][0] + ldsoff), 16, 0, 0);
    __syncthreads();

    int cur = 0;
#pragma unroll 1
    for (int kt = 0; kt < 32; ++kt) {
        if (kt + 1 < 32) {
            __builtin_amdgcn_global_load_lds(
                (const __attribute__((address_space(1))) void*)(kstage + (size_t)(kt + 1) * 4096),
                (__attribute__((address_space(3))) void*)((char*)&Ks[cur ^ 1][0] + ldsoff), 16, 0, 0);
            __builtin_amdgcn_global_load_lds(
                (const __attribute__((address_space(1))) void*)(vstage + (size_t)(kt + 1) * 64),
                (__attribute__((address_space(3))) void*)((char*)&Vs[cur ^ 1][0] + ldsoff), 16, 0, 0);
        }

        const char* Ksc = (const char*)&Ks[cur][0];
        const char* Vsc = (const char*)&Vs[cur][0];

        bf16x8 kf0[4], kf1[4];
#pragma unroll
        for (int f = 0; f < 4; ++f) {
            int ch = (f << 1) | hi;
            kf0[f] = *(const bf16x8*)(Ksc + lm * 128 + ((ch ^ swz) << 4));
            kf1[f] = *(const bf16x8*)(Ksc + (lm + 32) * 128 + ((ch ^ swz) << 4));
        }
        bf16x8 vf0[4], vf1[4];
#pragma unroll
        for (int ks = 0; ks < 4; ++ks) {
            int ch = (ks << 1) | hi;
            vf0[ks] = *(const bf16x8*)(Vsc + lm * 128 + ((ch ^ swz) << 4));
            vf1[ks] = *(const bf16x8*)(Vsc + (lm + 32) * 128 + ((ch ^ swz) << 4));
        }

        // S^T = K · Q^T
        f32x16 s0 = {}, s1 = {};
#pragma unroll
        for (int f = 0; f < 4; ++f) {
            s0 = MFMA32(kf0[f], qf[f], s0);
            s1 = MFMA32(kf1[f], qf[f], s1);
        }

        // speculative P = exp2(S - mrow_old): starts immediately, overlaps max reduction
        float pe0[16], pe1[16];
#pragma unroll
        for (int r = 0; r < 16; ++r) pe0[r] = __builtin_amdgcn_exp2f(s0[r] - mrow);
#pragma unroll
        for (int r = 0; r < 16; ++r) pe1[r] = __builtin_amdgcn_exp2f(s1[r] - mrow);

        // tile row-max (tree + cross-half swap)
        float t8[8];
#pragma unroll
        for (int r = 0; r < 8; ++r)
            t8[r] = fmaxf(fmaxf(s0[r], s0[r + 8]), fmaxf(s1[r], s1[r + 8]));
#pragma unroll
        for (int st = 4; st; st >>= 1)
#pragma unroll
            for (int r = 0; r < st; ++r) t8[r] = fmaxf(t8[r], t8[r + st]);
        float pm = swapred_max(t8[0]);

        // defer-max: rescale (and redo exp with the new max) only when max grew > 8
        if (!__all(pm <= mrow + 8.0f)) {
            float mnew = fmaxf(mrow, pm);
            float corr = __builtin_amdgcn_exp2f(mrow - mnew);
            lsum *= corr;
            O0 *= corr;
            O1 *= corr;
            mrow = mnew;
#pragma unroll
            for (int r = 0; r < 16; ++r) pe0[r] = __builtin_amdgcn_exp2f(s0[r] - mrow);
#pragma unroll
            for (int r = 0; r < 16; ++r) pe1[r] = __builtin_amdgcn_exp2f(s1[r] - mrow);
        }

        // lane-local row-sum (cross-half swap deferred to epilogue)
        float u8[8];
#pragma unroll
        for (int r = 0; r < 8; ++r) u8[r] = (pe0[r] + pe0[r + 8]) + (pe1[r] + pe1[r + 8]);
#pragma unroll
        for (int st = 4; st; st >>= 1)
#pragma unroll
            for (int r = 0; r < st; ++r) u8[r] = u8[r] + u8[r + st];
        lsum += u8[0];

        // redistribute P into PV B-frags (in-register, shfl_xor 32)
        bf16x8 pf[4];
        pack_frags(pe0, hi, pf[0], pf[1]);
        pack_frags(pe1, hi, pf[2], pf[3]);

        // O^T += Vt · P^T
#pragma unroll
        for (int ks = 0; ks < 4; ++ks) {
            O0 = MFMA32(vf0[ks], pf[ks], O0);
            O1 = MFMA32(vf1[ks], pf[ks], O1);
        }

        __syncthreads();
        cur ^= 1;
    }

    float lrow = swapred_sum(lsum);
    float inv = 1.0f / lrow;
    bf16* op = Out + ((size_t)bb * 2048 + qrow) * 1024 + h * 64 + 4 * hi;
#pragma unroll
    for (int t = 0; t < 4; ++t) {
        bf16x4 w0, w1;
#pragma unroll
        for (int e = 0; e < 4; ++e) {
            w0[e] = (bf16)(O0[4 * t + e] * inv);
            w1[e] = (bf16)(O1[4 * t + e] * inv);
        }
        *(bf16x4*)(op + 8 * t)      = w0;   // d = 4*hi + 8*t + e
        *(bf16x4*)(op + 32 + 8 * t) = w1;   // + 32
    }
}

extern "C" void kernel_launch(void* const* d_in, const int* in_sizes, int n_in,
                              void* d_out, int out_size, void* d_ws, size_t ws_size,
                              hipStream_t stream) {
    const float* q  = (const float*)d_in[0];
    const float* k  = (const float*)d_in[1];
    const float* v  = (const float*)d_in[2];
    const float* Wq = (const float*)d_in[3];
    const float* bq = (const float*)d_in[4];
    const float* Wk = (const float*)d_in[5];
    const float* bk = (const float*)d_in[6];
    const float* Wv = (const float*)d_in[7];
    const float* bv = (const float*)d_in[8];
    const float* Wo = (const float*)d_in[9];
    const float* bo = (const float*)d_in[10];

    char* ws = (char*)d_ws;
    const size_t MB = 1ull << 20;
    const dim3 twg(16, 16), blk(256);

    if (ws_size >= 40 * MB) {
        // fused path (40 MB): no cvt pass, no combine
        bf16* Wtq = (bf16*)(ws + 0 * MB);
        bf16* Wtk = (bf16*)(ws + 2 * MB);
        bf16* Wtv = (bf16*)(ws + 4 * MB);
        bf16* Wto = (bf16*)(ws + 6 * MB);
        bf16* Qb  = (bf16*)(ws + 8 * MB);
        bf16* Kb  = (bf16*)(ws + 16 * MB);
        bf16* Vtb = (bf16*)(ws + 24 * MB);
        bf16* AOb = (bf16*)(ws + 32 * MB);

        k_transpose_w4<<<dim3(16, 16, 4), blk, 0, stream>>>(Wq, Wk, Wv, Wo, Wtq, Wtk, Wtv, Wto);
        k_gemm_qkv<<<768, blk, 0, stream>>>(q, k, v, Wtq, Wtk, Wtv, bq, bk, bv, Qb, Kb, Vtb);
        k_attn<<<256, 512, 0, stream>>>(Qb, Kb, Vtb, AOb);
        k_gemm_out<<<512, blk, 0, stream>>>(AOb, Wto, bo, (float*)d_out);
    } else {
        // sequential fallback (34 MB ws)
        bf16* Wt   = (bf16*)(ws + 0 * MB);
        bf16* Qb   = (bf16*)(ws + 2 * MB);
        bf16* Kb   = (bf16*)(ws + 10 * MB);
        bf16* Vtb  = (bf16*)(ws + 18 * MB);
        bf16* AOb  = (bf16*)(ws + 26 * MB);

        k_transpose_w<<<twg, blk, 0, stream>>>(Wq, Wt, QSCL);
        k_gemm_proj<<<256, blk, 0, stream>>>(q, Wt, bq, QSCL, (void*)Qb);
        k_transpose_w<<<twg, blk, 0, stream>>>(Wk, Wt, 1.0f);
        k_gemm_proj<<<256, blk, 0, stream>>>(k, Wt, bk, 1.0f, (void*)Kb);
        k_transpose_w<<<twg, blk, 0, stream>>>(Wv, Wt, 1.0f);
        k_gemm_vt<<<256, blk, 0, stream>>>(Wt, v, bv, Vtb);
        k_transpose_w<<<twg, blk, 0, stream>>>(Wo, Wt, 1.0f);
        k_attn<<<256, 512, 0, stream>>>(Qb, Kb, Vtb, AOb);
        k_gemm_out<<<512, blk, 0, stream>>>(AOb, Wt, bo, (float*)d_out);
    }
}

// Round 17
// 136.943 us; speedup vs baseline: 1.1347x; 1.0078x over previous
//
#include <hip/hip_runtime.h>
#include <hip/hip_bf16.h>
#include <stdint.h>

typedef __bf16 bf16;
typedef __bf16 bf16x8 __attribute__((ext_vector_type(8)));
typedef __bf16 bf16x4 __attribute__((ext_vector_type(4)));
typedef float  f32x4  __attribute__((ext_vector_type(4)));
typedef float  f32x16 __attribute__((ext_vector_type(16)));
typedef uint32_t u32;

#define MFMA16(a,b,c) __builtin_amdgcn_mfma_f32_16x16x32_bf16((a),(b),(c),0,0,0)
#define MFMA32(a,b,c) __builtin_amdgcn_mfma_f32_32x32x16_bf16((a),(b),(c),0,0,0)

// 0.125 (1/sqrt(64)) * log2(e): folded into Wq/bq so softmax runs in exp2 domain.
#define QSCL 0.1803368801111204f

// ---------- helpers ----------
__device__ __forceinline__ u32 sx32(u32 x) {  // value from lane^32 (HW-verified r3)
    return (u32)__shfl_xor((int)x, 32, 64);
}
__device__ __forceinline__ float swapred_max(float v) {
    return fmaxf(v, __builtin_bit_cast(float, sx32(__builtin_bit_cast(u32, v))));
}
__device__ __forceinline__ float swapred_sum(float v) {
    return v + __builtin_bit_cast(float, sx32(__builtin_bit_cast(u32, v)));
}
__device__ __forceinline__ u32 pkbf(float lo, float hi) {
    union { bf16 h[2]; u32 u; } un;
    un.h[0] = (bf16)lo; un.h[1] = (bf16)hi;
    return un.u;
}
// p[16] = exp'd scores for one 32-row K-block; lane (lm,hi) holds k_local(r) =
// (r&3) + 8*(r>>2) + 4*hi for col q=lm. Produce PV B-frags f0 (k=0..15) and
// f1 (k=16..31): lane needs k = 16*ks + hi*8 + j (j=0..7) at col q=lm.
__device__ __forceinline__ void pack_frags(const float* p, int hi, bf16x8& f0, bf16x8& f1) {
    u32 k01 = pkbf(p[0],  p[1]),  k23 = pkbf(p[2],  p[3]);
    u32 k45 = pkbf(p[4],  p[5]),  k67 = pkbf(p[6],  p[7]);
    u32 k89 = pkbf(p[8],  p[9]),  kab = pkbf(p[10], p[11]);
    u32 kcd = pkbf(p[12], p[13]), kef = pkbf(p[14], p[15]);
    u32 x01 = sx32(k01), x23 = sx32(k23), x45 = sx32(k45), x67 = sx32(k67);
    u32 x89 = sx32(k89), xab = sx32(kab), xcd = sx32(kcd), xef = sx32(kef);
    union { u32 w[4]; bf16x8 v; } u0, u1;
    u0.w[0] = hi ? x45 : k01;  u0.w[1] = hi ? x67 : k23;
    u0.w[2] = hi ? k45 : x01;  u0.w[3] = hi ? k67 : x23;
    u1.w[0] = hi ? xcd : k89;  u1.w[1] = hi ? xef : kab;
    u1.w[2] = hi ? kcd : x89;  u1.w[3] = hi ? kef : xab;
    f0 = u0.v; f1 = u1.v;
}

// ---------------- weight transpose: W[k][n] fp32 -> Wt[n][k] bf16 (* scale) ----------------
__device__ __forceinline__ void transpose_body(const float* __restrict__ W, bf16* __restrict__ Wt,
                                               float scale, int n0, int k0) {
    __shared__ bf16 t[64][65];
    for (int i = 0; i < 16; ++i) {
        int idx = threadIdx.x + i * 256, r = idx >> 6, c = idx & 63;
        t[r][c] = (bf16)(W[(size_t)(k0 + r) * 1024 + n0 + c] * scale);
    }
    __syncthreads();
    for (int i = 0; i < 16; ++i) {
        int idx = threadIdx.x + i * 256, r = idx >> 6, c = idx & 63;
        Wt[(size_t)(n0 + r) * 1024 + k0 + c] = t[c][r];
    }
}
__global__ __launch_bounds__(256) void k_transpose_w(const float* __restrict__ W,
                                                     bf16* __restrict__ Wt, float scale) {
    transpose_body(W, Wt, scale, blockIdx.x * 64, blockIdx.y * 64);
}
// all four weights in one launch (grid 16x16x4)
__global__ __launch_bounds__(256) void k_transpose_w4(const float* __restrict__ Wq, const float* __restrict__ Wk,
                                                      const float* __restrict__ Wv, const float* __restrict__ Wo,
                                                      bf16* __restrict__ Wtq, bf16* __restrict__ Wtk,
                                                      bf16* __restrict__ Wtv, bf16* __restrict__ Wto) {
    int z = blockIdx.z;
    const float* W = (z == 0) ? Wq : (z == 1) ? Wk : (z == 2) ? Wv : Wo;
    bf16* Wt = (z == 0) ? Wtq : (z == 1) ? Wtk : (z == 2) ? Wtv : Wto;
    transpose_body(W, Wt, (z == 0) ? QSCL : 1.0f, blockIdx.x * 64, blockIdx.y * 64);
}

// ---------------- mixed GEMM tile (R11-proven, best measured), 128x128, K=1024 ----------------
// One operand fp32 (reg-staged with in-staging bf16 cvt), the other bf16 (glds).
// out_mode 0: bf16 head layout [b][h][s][d]; out_mode 2: bf16 Vt layout [bh][d][s].
template <int A_F32, int B_F32>
__device__ __forceinline__ void gemm_tile2(const void* __restrict__ Ap, const void* __restrict__ Btp,
                                           const float* __restrict__ bias, float bscale,
                                           void* __restrict__ Cp, int out_mode, int m0, int n0,
                                           bf16 (*As)[64], bf16 (*Bs)[64]) {
    const int tid = threadIdx.x;
    const int wid = tid >> 6, lane = tid & 63, lg = lane >> 4, lm = lane & 15;
    const int wr = wid >> 1, wc = wid & 1;
    const int grow = tid >> 3, gcol = (tid & 7) << 3;

    f32x4 acc[4][4] = {};

    for (int kt = 0; kt < 16; ++kt) {
        const int k0 = kt << 6;
        __syncthreads();
#pragma unroll
        for (int p = 0; p < 4; ++p) {
            const int r = p * 32 + grow;
            if constexpr (A_F32) {
                const float* A = (const float*)Ap;
                const float* src = A + (size_t)(m0 + r) * 1024 + k0 + gcol;
                float4 v0 = *(const float4*)src;
                float4 v1 = *(const float4*)(src + 4);
                bf16x8 w = {(bf16)v0.x, (bf16)v0.y, (bf16)v0.z, (bf16)v0.w,
                            (bf16)v1.x, (bf16)v1.y, (bf16)v1.z, (bf16)v1.w};
                *(bf16x8*)&As[r][gcol] = w;
            } else {
                const bf16* A = (const bf16*)Ap;
                __builtin_amdgcn_global_load_lds(
                    (const __attribute__((address_space(1))) void*)(A + (size_t)(m0 + r) * 1024 + k0 + gcol),
                    (__attribute__((address_space(3))) void*)(&As[p * 32 + wid * 8][0]), 16, 0, 0);
            }
            if constexpr (B_F32) {
                const float* B = (const float*)Btp;
                const float* src = B + (size_t)(n0 + r) * 1024 + k0 + gcol;
                float4 v0 = *(const float4*)src;
                float4 v1 = *(const float4*)(src + 4);
                bf16x8 w = {(bf16)v0.x, (bf16)v0.y, (bf16)v0.z, (bf16)v0.w,
                            (bf16)v1.x, (bf16)v1.y, (bf16)v1.z, (bf16)v1.w};
                *(bf16x8*)&Bs[r][gcol] = w;
            } else {
                const bf16* Bt = (const bf16*)Btp;
                __builtin_amdgcn_global_load_lds(
                    (const __attribute__((address_space(1))) void*)(Bt + (size_t)(n0 + r) * 1024 + k0 + gcol),
                    (__attribute__((address_space(3))) void*)(&Bs[p * 32 + wid * 8][0]), 16, 0, 0);
            }
        }
        __syncthreads();
#pragma unroll
        for (int kk = 0; kk < 2; ++kk) {
            bf16x8 a[4], b[4];
#pragma unroll
            for (int i = 0; i < 4; ++i) a[i] = *(const bf16x8*)&As[wr * 64 + i * 16 + lm][kk * 32 + lg * 8];
#pragma unroll
            for (int j = 0; j < 4; ++j) b[j] = *(const bf16x8*)&Bs[wc * 64 + j * 16 + lm][kk * 32 + lg * 8];
#pragma unroll
            for (int i = 0; i < 4; ++i)
#pragma unroll
                for (int j = 0; j < 4; ++j) acc[i][j] = MFMA16(a[i], b[j], acc[i][j]);
        }
    }

    for (int i = 0; i < 4; ++i) {
        for (int j = 0; j < 4; ++j) {
            int col = n0 + wc * 64 + j * 16 + lm;
            for (int q = 0; q < 4; ++q) {
                int row = m0 + wr * 64 + i * 16 + lg * 4 + q;
                if (out_mode == 0) {  // bf16 head layout [b][h][s][d]
                    float val = acc[i][j][q] + bscale * bias[col];
                    int bb = row >> 11, s = row & 2047, h = col >> 6, d = col & 63;
                    ((bf16*)Cp)[(((size_t)bb * 16 + h) * 2048 + s) * 64 + d] = (bf16)val;
                } else {              // Vt layout [bh][d][s], bias per ROW
                    float val = acc[i][j][q] + bias[row];
                    size_t idx = (((size_t)(col >> 11) * 16 + (row >> 6)) * 64 + (row & 63)) * 2048 + (col & 2047);
                    ((bf16*)Cp)[idx] = (bf16)val;
                }
            }
        }
    }
}

// XCD-stripe decode for M=4096,N=1024: xcd owns m-tiles 4*xcd..4*xcd+3.
__device__ __forceinline__ void tile_decode(int r, int& m0, int& n0) {
    int xcd = r & 7, slot = (r >> 3) & 3, n = (r >> 5) & 7;
    m0 = (xcd * 4 + slot) * 128;
    n0 = n * 128;
}
// decode for Vt gemm (M=1024 weight-rows, N=4096 seq): xcd owns 4 n-tiles.
__device__ __forceinline__ void tile_decode_vt(int r, int& m0, int& n0) {
    int xcd = r & 7, loc = r >> 3;       // loc in [0,32)
    int nslot = loc & 3, m = loc >> 2;   // m in [0,8)
    n0 = (xcd * 4 + nslot) * 128;
    m0 = m * 128;
}

// Q/K projection (A = fp32 activation, Bt = bf16 weight)
__global__ __launch_bounds__(256, 4) void k_gemm_proj(const float* __restrict__ A,
                                                      const bf16* __restrict__ Bt,
                                                      const float* __restrict__ bias, float bscale,
                                                      void* __restrict__ Cp) {
    __shared__ bf16 As[128][64];
    __shared__ bf16 Bs[128][64];
    int m0, n0;
    tile_decode(blockIdx.x, m0, n0);
    gemm_tile2<1, 0>((const void*)A, (const void*)Bt, bias, bscale, Cp, 0, m0, n0, As, Bs);
}

// V projection producing Vt directly (A = bf16 weight, Bt = fp32 activation)
__global__ __launch_bounds__(256, 4) void k_gemm_vt(const bf16* __restrict__ Wtv,
                                                    const float* __restrict__ v,
                                                    const float* __restrict__ bias,
                                                    bf16* __restrict__ Vtb) {
    __shared__ bf16 As[128][64];
    __shared__ bf16 Bs[128][64];
    int m0, n0;
    tile_decode_vt(blockIdx.x, m0, n0);
    gemm_tile2<0, 1>((const void*)Wtv, (const void*)v, bias, 1.0f, (void*)Vtb, 2, m0, n0, As, Bs);
}

// fused Q/K/V projections with in-staging fp32->bf16 cvt: grid 768 (3 blocks/CU)
__global__ __launch_bounds__(256, 4) void k_gemm_qkv(const float* __restrict__ q, const float* __restrict__ k,
                                                     const float* __restrict__ v,
                                                     const bf16* __restrict__ Wtq, const bf16* __restrict__ Wtk,
                                                     const bf16* __restrict__ Wtv,
                                                     const float* __restrict__ bq, const float* __restrict__ bk,
                                                     const float* __restrict__ bv,
                                                     bf16* __restrict__ Qb, bf16* __restrict__ Kb,
                                                     bf16* __restrict__ Vtb) {
    __shared__ bf16 As[128][64];
    __shared__ bf16 Bs[128][64];
    int l = blockIdx.x, z = l >> 8, r = l & 255;
    int m0, n0;
    if (z == 2) {
        tile_decode_vt(r, m0, n0);
        // A = bf16 weight Wtv, Bt = fp32 activation v (operand order is load-type-critical)
        gemm_tile2<0, 1>((const void*)Wtv, (const void*)v, bv, 1.0f, (void*)Vtb, 2, m0, n0, As, Bs);
    } else {
        tile_decode(r, m0, n0);
        const float* A  = (z == 0) ? q : k;
        const bf16* Bt  = (z == 0) ? Wtq : Wtk;
        const float* bias = (z == 0) ? bq : bk;
        float bscale = (z == 0) ? QSCL : 1.0f;
        bf16* Cp = (z == 0) ? Qb : Kb;
        gemm_tile2<1, 0>((const void*)A, (const void*)Bt, bias, bscale, (void*)Cp, 0, m0, n0, As, Bs);
    }
}

// ---------------- output projection: 128x64 tiles, 512 blocks (2/CU) ----------------
__global__ __launch_bounds__(256, 4) void k_gemm_out(const bf16* __restrict__ A,
                                                     const bf16* __restrict__ Bt,
                                                     const float* __restrict__ bias,
                                                     float* __restrict__ C) {
    __shared__ bf16 As[128][64];
    __shared__ bf16 Bs[64][64];
    const int tid = threadIdx.x;
    const int wid = tid >> 6, lane = tid & 63, lg = lane >> 4, lm = lane & 15;
    const int grow = tid >> 3, gcol = (tid & 7) << 3;
    const int r = blockIdx.x;
    const int xcd = r & 7, loc = r >> 3;
    const int mslot = loc & 3, n = loc >> 2;
    const int m0 = (xcd * 4 + mslot) * 128, n0 = n * 64;

    f32x4 acc[2][4] = {};

    for (int kt = 0; kt < 16; ++kt) {
        const int k0 = kt << 6;
        __syncthreads();
#pragma unroll
        for (int p = 0; p < 4; ++p)
            __builtin_amdgcn_global_load_lds(
                (const __attribute__((address_space(1))) void*)(A + (size_t)(m0 + p * 32 + grow) * 1024 + k0 + gcol),
                (__attribute__((address_space(3))) void*)(&As[p * 32 + wid * 8][0]), 16, 0, 0);
#pragma unroll
        for (int p = 0; p < 2; ++p)
            __builtin_amdgcn_global_load_lds(
                (const __attribute__((address_space(1))) void*)(Bt + (size_t)(n0 + p * 32 + grow) * 1024 + k0 + gcol),
                (__attribute__((address_space(3))) void*)(&Bs[p * 32 + wid * 8][0]), 16, 0, 0);
        __syncthreads();
#pragma unroll
        for (int kk = 0; kk < 2; ++kk) {
            bf16x8 a[2], b[4];
#pragma unroll
            for (int i = 0; i < 2; ++i) a[i] = *(const bf16x8*)&As[wid * 32 + i * 16 + lm][kk * 32 + lg * 8];
#pragma unroll
            for (int j = 0; j < 4; ++j) b[j] = *(const bf16x8*)&Bs[j * 16 + lm][kk * 32 + lg * 8];
#pragma unroll
            for (int i = 0; i < 2; ++i)
#pragma unroll
                for (int j = 0; j < 4; ++j) acc[i][j] = MFMA16(a[i], b[j], acc[i][j]);
        }
    }

    for (int i = 0; i < 2; ++i) {
        for (int j = 0; j < 4; ++j) {
            int col = n0 + j * 16 + lm;
            float bv = bias[col];
            for (int q = 0; q < 4; ++q) {
                int row = m0 + wid * 32 + i * 16 + lg * 4 + q;
                C[(size_t)row * 1024 + col] = acc[i][j][q] + bv;
            }
        }
    }
}

// ---------------- flash attention: 8-wave block, LDS-staged K/V (R11-proven, 69.4 us) ----------------
// Speculative exp (overlaps max-tree latency) + deferred cross-half l-sum; direct
// normalized output write.
// Q,K: [bh][2048][64] bf16 (Q pre-scaled); Vt: [bh][64][2048]; Out: [b][s][h*64+d] bf16.
__global__ __launch_bounds__(512, 2) void k_attn(const bf16* __restrict__ Q,
                                                 const bf16* __restrict__ Kb,
                                                 const bf16* __restrict__ Vt,
                                                 bf16* __restrict__ Out) {
    __shared__ bf16 Ks[2][64 * 64];
    __shared__ bf16 Vs[2][64 * 64];
    const int tid = threadIdx.x;
    const int wid = tid >> 6, lane = tid & 63;
    const int lm = lane & 31, hi = lane >> 5;
    const int bid = blockIdx.x;
    const int bh = bid & 31, qt = bid >> 5;   // same-bh blocks share an XCD's L2
    const int bb = bh >> 4, h = bh & 15;
    const int qrow = qt * 256 + wid * 32 + lm;
    const size_t qk_base = (size_t)bh * (2048 * 64);
    const size_t vt_base = (size_t)bh * (64 * 2048);

    // staging geometry (proven r6): LDS[row][c] = global[row][c ^ (row&7)] via source swizzle
    const int srow = tid >> 3, sc8 = tid & 7;
    const int cse = (sc8 ^ (srow & 7)) * 8;
    const bf16* kstage = Kb + qk_base + (size_t)srow * 64 + cse;     // + kt*4096
    const bf16* vstage = Vt + vt_base + (size_t)srow * 2048 + cse;   // + kt*64
    const int ldsoff = wid * 1024;

    bf16x8 qf[4];
    {
        const bf16* qp = Q + qk_base + (size_t)qrow * 64 + hi * 8;
#pragma unroll
        for (int f = 0; f < 4; ++f) qf[f] = *(const bf16x8*)(qp + f * 16);
    }

    f32x16 O0 = {}, O1 = {};
    float mrow = -1e30f, lsum = 0.f;   // lsum = this lane's half; cross-half sum deferred

    const int swz = (lm & 7);

    __builtin_amdgcn_global_load_lds(
        (const __attribute__((address_space(1))) void*)(kstage),
        (__attribute__((address_space(3))) void*)((char*)&Ks[0][0] + ldsoff), 16, 0, 0);
    __builtin_amdgcn_global_load_lds(
        (const __attribute__((address_space(1))) void*)(vstage),
        (__attribute__((address_space(3))) void*)((char*)&Vs[0][0] + ldsoff), 16, 0, 0);
    __syncthreads();

    int cur = 0;
#pragma unroll 1
    for (int kt = 0; kt < 32; ++kt) {
        if (kt + 1 < 32) {
            __builtin_amdgcn_global_load_lds(
                (const __attribute__((address_space(1))) void*)(kstage + (size_t)(kt + 1) * 4096),
                (__attribute__((address_space(3))) void*)((char*)&Ks[cur ^ 1][0] + ldsoff), 16, 0, 0);
            __builtin_amdgcn_global_load_lds(
                (const __attribute__((address_space(1))) void*)(vstage + (size_t)(kt + 1) * 64),
                (__attribute__((address_space(3))) void*)((char*)&Vs[cur ^ 1][0] + ldsoff), 16, 0, 0);
        }

        const char* Ksc = (const char*)&Ks[cur][0];
        const char* Vsc = (const char*)&Vs[cur][0];

        bf16x8 kf0[4], kf1[4];
#pragma unroll
        for (int f = 0; f < 4; ++f) {
            int ch = (f << 1) | hi;
            kf0[f] = *(const bf16x8*)(Ksc + lm * 128 + ((ch ^ swz) << 4));
            kf1[f] = *(const bf16x8*)(Ksc + (lm + 32) * 128 + ((ch ^ swz) << 4));
        }
        bf16x8 vf0[4], vf1[4];
#pragma unroll
        for (int ks = 0; ks < 4; ++ks) {
            int ch = (ks << 1) | hi;
            vf0[ks] = *(const bf16x8*)(Vsc + lm * 128 + ((ch ^ swz) << 4));
            vf1[ks] = *(const bf16x8*)(Vsc + (lm + 32) * 128 + ((ch ^ swz) << 4));
        }

        // S^T = K · Q^T
        f32x16 s0 = {}, s1 = {};
#pragma unroll
        for (int f = 0; f < 4; ++f) {
            s0 = MFMA32(kf0[f], qf[f], s0);
            s1 = MFMA32(kf1[f], qf[f], s1);
        }

        // speculative P = exp2(S - mrow_old): starts immediately, overlaps max reduction
        float pe0[16], pe1[16];
#pragma unroll
        for (int r = 0; r < 16; ++r) pe0[r] = __builtin_amdgcn_exp2f(s0[r] - mrow);
#pragma unroll
        for (int r = 0; r < 16; ++r) pe1[r] = __builtin_amdgcn_exp2f(s1[r] - mrow);

        // tile row-max (tree + cross-half swap)
        float t8[8];
#pragma unroll
        for (int r = 0; r < 8; ++r)
            t8[r] = fmaxf(fmaxf(s0[r], s0[r + 8]), fmaxf(s1[r], s1[r + 8]));
#pragma unroll
        for (int st = 4; st; st >>= 1)
#pragma unroll
            for (int r = 0; r < st; ++r) t8[r] = fmaxf(t8[r], t8[r + st]);
        float pm = swapred_max(t8[0]);

        // defer-max: rescale (and redo exp with the new max) only when max grew > 8
        if (!__all(pm <= mrow + 8.0f)) {
            float mnew = fmaxf(mrow, pm);
            float corr = __builtin_amdgcn_exp2f(mrow - mnew);
            lsum *= corr;
            O0 *= corr;
            O1 *= corr;
            mrow = mnew;
#pragma unroll
            for (int r = 0; r < 16; ++r) pe0[r] = __builtin_amdgcn_exp2f(s0[r] - mrow);
#pragma unroll
            for (int r = 0; r < 16; ++r) pe1[r] = __builtin_amdgcn_exp2f(s1[r] - mrow);
        }

        // lane-local row-sum (cross-half swap deferred to epilogue)
        float u8[8];
#pragma unroll
        for (int r = 0; r < 8; ++r) u8[r] = (pe0[r] + pe0[r + 8]) + (pe1[r] + pe1[r + 8]);
#pragma unroll
        for (int st = 4; st; st >>= 1)
#pragma unroll
            for (int r = 0; r < st; ++r) u8[r] = u8[r] + u8[r + st];
        lsum += u8[0];

        // redistribute P into PV B-frags (in-register, shfl_xor 32)
        bf16x8 pf[4];
        pack_frags(pe0, hi, pf[0], pf[1]);
        pack_frags(pe1, hi, pf[2], pf[3]);

        // O^T += Vt · P^T
#pragma unroll
        for (int ks = 0; ks < 4; ++ks) {
            O0 = MFMA32(vf0[ks], pf[ks], O0);
            O1 = MFMA32(vf1[ks], pf[ks], O1);
        }

        __syncthreads();
        cur ^= 1;
    }

    float lrow = swapred_sum(lsum);
    float inv = 1.0f / lrow;
    bf16* op = Out + ((size_t)bb * 2048 + qrow) * 1024 + h * 64 + 4 * hi;
#pragma unroll
    for (int t = 0; t < 4; ++t) {
        bf16x4 w0, w1;
#pragma unroll
        for (int e = 0; e < 4; ++e) {
            w0[e] = (bf16)(O0[4 * t + e] * inv);
            w1[e] = (bf16)(O1[4 * t + e] * inv);
        }
        *(bf16x4*)(op + 8 * t)      = w0;   // d = 4*hi + 8*t + e
        *(bf16x4*)(op + 32 + 8 * t) = w1;   // + 32
    }
}

extern "C" void kernel_launch(void* const* d_in, const int* in_sizes, int n_in,
                              void* d_out, int out_size, void* d_ws, size_t ws_size,
                              hipStream_t stream) {
    const float* q  = (const float*)d_in[0];
    const float* k  = (const float*)d_in[1];
    const float* v  = (const float*)d_in[2];
    const float* Wq = (const float*)d_in[3];
    const float* bq = (const float*)d_in[4];
    const float* Wk = (const float*)d_in[5];
    const float* bk = (const float*)d_in[6];
    const float* Wv = (const float*)d_in[7];
    const float* bv = (const float*)d_in[8];
    const float* Wo = (const float*)d_in[9];
    const float* bo = (const float*)d_in[10];

    char* ws = (char*)d_ws;
    const size_t MB = 1ull << 20;
    const dim3 twg(16, 16), blk(256);

    if (ws_size >= 40 * MB) {
        // fused path (40 MB): no cvt pass, no combine (best measured: 136.7 us)
        bf16* Wtq = (bf16*)(ws + 0 * MB);
        bf16* Wtk = (bf16*)(ws + 2 * MB);
        bf16* Wtv = (bf16*)(ws + 4 * MB);
        bf16* Wto = (bf16*)(ws + 6 * MB);
        bf16* Qb  = (bf16*)(ws + 8 * MB);
        bf16* Kb  = (bf16*)(ws + 16 * MB);
        bf16* Vtb = (bf16*)(ws + 24 * MB);
        bf16* AOb = (bf16*)(ws + 32 * MB);

        k_transpose_w4<<<dim3(16, 16, 4), blk, 0, stream>>>(Wq, Wk, Wv, Wo, Wtq, Wtk, Wtv, Wto);
        k_gemm_qkv<<<768, blk, 0, stream>>>(q, k, v, Wtq, Wtk, Wtv, bq, bk, bv, Qb, Kb, Vtb);
        k_attn<<<256, 512, 0, stream>>>(Qb, Kb, Vtb, AOb);
        k_gemm_out<<<512, blk, 0, stream>>>(AOb, Wto, bo, (float*)d_out);
    } else {
        // sequential fallback (34 MB ws)
        bf16* Wt   = (bf16*)(ws + 0 * MB);
        bf16* Qb   = (bf16*)(ws + 2 * MB);
        bf16* Kb   = (bf16*)(ws + 10 * MB);
        bf16* Vtb  = (bf16*)(ws + 18 * MB);
        bf16* AOb  = (bf16*)(ws + 26 * MB);

        k_transpose_w<<<twg, blk, 0, stream>>>(Wq, Wt, QSCL);
        k_gemm_proj<<<256, blk, 0, stream>>>(q, Wt, bq, QSCL, (void*)Qb);
        k_transpose_w<<<twg, blk, 0, stream>>>(Wk, Wt, 1.0f);
        k_gemm_proj<<<256, blk, 0, stream>>>(k, Wt, bk, 1.0f, (void*)Kb);
        k_transpose_w<<<twg, blk, 0, stream>>>(Wv, Wt, 1.0f);
        k_gemm_vt<<<256, blk, 0, stream>>>(Wt, v, bv, Vtb);
        k_transpose_w<<<twg, blk, 0, stream>>>(Wo, Wt, 1.0f);
        k_attn<<<256, 512, 0, stream>>>(Qb, Kb, Vtb, AOb);
        k_gemm_out<<<512, blk, 0, stream>>>(AOb, Wt, bo, (float*)d_out);
    }
}